// Round 1
// baseline (519.804 us; speedup 1.0000x reference)
//
#include <hip/hip_runtime.h>
#include <hip/hip_bf16.h>
#include <math.h>

// Problem constants (derived from in_sizes at launch where possible)
#define FH 128     // hidden = heads(4) * C(32)
#define NEG_SLOPE 0.2f
#define BN_EPS 1e-5f

// ---------------------------------------------------------------------------
// GEMM1: h1 = x @ W1   [N,128] @ [128,128]
// block = 256 threads computes 32 rows x 64 cols; grid = (ceil(N/32), 2)
// ---------------------------------------------------------------------------
__global__ __launch_bounds__(256) void k_gemm1(const float* __restrict__ x,
                                               const float* __restrict__ W,
                                               float* __restrict__ h1, int N) {
    __shared__ float xs[32][132];   // +4 pad: xs[r][k] bank = (4r+k)%32, conflict-free
    __shared__ float Ws[128][64];
    const int t = threadIdx.x;
    const int row0 = blockIdx.x * 32;
    const int col0 = blockIdx.y * 64;

    // load x tile: 32x128 floats, 4 float4 per thread, coalesced
    #pragma unroll
    for (int i = 0; i < 4; ++i) {
        int f4 = i * 256 + t;          // float4 index
        int f  = f4 * 4;
        int r  = f >> 7, c = f & 127;
        float4 v = make_float4(0.f, 0.f, 0.f, 0.f);
        if (row0 + r < N) v = *(const float4*)(x + (size_t)(row0 + r) * FH + c);
        xs[r][c]     = v.x; xs[r][c + 1] = v.y;
        xs[r][c + 2] = v.z; xs[r][c + 3] = v.w;
    }
    // load W tile: 128x64 floats, 8 float4 per thread, coalesced
    #pragma unroll
    for (int i = 0; i < 8; ++i) {
        int f4 = i * 256 + t;
        int f  = f4 * 4;
        int k  = f >> 6, c = f & 63;
        float4 v = *(const float4*)(W + (size_t)k * FH + col0 + c);
        *(float4*)&Ws[k][c] = v;
    }
    __syncthreads();

    const int r  = t >> 3;          // 0..31
    const int cq = (t & 7) * 8;     // 0..56
    float acc[8] = {0, 0, 0, 0, 0, 0, 0, 0};
    #pragma unroll 4
    for (int k = 0; k < 128; ++k) {
        float xv = xs[r][k];
        float4 w0 = *(const float4*)&Ws[k][cq];
        float4 w1 = *(const float4*)&Ws[k][cq + 4];
        acc[0] = fmaf(xv, w0.x, acc[0]); acc[1] = fmaf(xv, w0.y, acc[1]);
        acc[2] = fmaf(xv, w0.z, acc[2]); acc[3] = fmaf(xv, w0.w, acc[3]);
        acc[4] = fmaf(xv, w1.x, acc[4]); acc[5] = fmaf(xv, w1.y, acc[5]);
        acc[6] = fmaf(xv, w1.z, acc[6]); acc[7] = fmaf(xv, w1.w, acc[7]);
    }
    int row = row0 + r;
    if (row < N) {
        float* p = h1 + (size_t)row * FH + col0 + cq;
        *(float4*)p       = make_float4(acc[0], acc[1], acc[2], acc[3]);
        *(float4*)(p + 4) = make_float4(acc[4], acc[5], acc[6], acc[7]);
    }
}

// ---------------------------------------------------------------------------
// per-(node, head) attention scores for layer 1
// ---------------------------------------------------------------------------
__global__ void k_scores1(const float* __restrict__ h1,
                          const float* __restrict__ asrc, const float* __restrict__ adst,
                          float* __restrict__ ssrc, float* __restrict__ sdst, int N) {
    int idx = blockIdx.x * blockDim.x + threadIdx.x;   // n*4 + h
    if (idx >= N * 4) return;
    int n = idx >> 2, h = idx & 3;
    const float4* hp = (const float4*)(h1 + (size_t)n * FH + h * 32);
    const float4* ap = (const float4*)(asrc + h * 32);
    const float4* bp = (const float4*)(adst + h * 32);
    float s1 = 0.f, s2 = 0.f;
    #pragma unroll
    for (int j = 0; j < 8; ++j) {
        float4 v = hp[j], a = ap[j], b = bp[j];
        s1 += v.x * a.x + v.y * a.y + v.z * a.z + v.w * a.w;
        s2 += v.x * b.x + v.y * b.y + v.z * b.z + v.w * b.w;
    }
    ssrc[idx] = s1;
    sdst[idx] = s2;
}

// ---------------------------------------------------------------------------
// CSR build: count incoming degree (incl. self loops), scan, scatter
// edge i<E: src=ei[i], dst=ei[E+i];  i in [E,E+N): self loop (i-E, i-E)
// ---------------------------------------------------------------------------
__global__ void k_count(const int* __restrict__ ei, int E, int N, int* __restrict__ deg) {
    int i = blockIdx.x * blockDim.x + threadIdx.x;
    if (i >= E + N) return;
    int d = (i < E) ? ei[E + i] : (i - E);
    atomicAdd(&deg[d], 1);
}

__global__ void k_scan(const int* __restrict__ deg, int* __restrict__ rowptr, int N) {
    __shared__ int buf[1024];
    __shared__ int carry;
    int t = threadIdx.x;
    if (t == 0) carry = 0;
    __syncthreads();
    for (int base = 0; base < N; base += 1024) {
        int i = base + t;
        int v = (i < N) ? deg[i] : 0;
        buf[t] = v;
        __syncthreads();
        for (int off = 1; off < 1024; off <<= 1) {
            int tmp = (t >= off) ? buf[t - off] : 0;
            __syncthreads();
            buf[t] += tmp;
            __syncthreads();
        }
        if (i < N) rowptr[i] = carry + buf[t] - v;   // exclusive
        __syncthreads();
        if (t == 1023) carry += buf[1023];
        __syncthreads();
    }
    if (t == 0) rowptr[N] = carry;
}

__global__ void k_fill(const int* __restrict__ ei, int E, int N,
                       const int* __restrict__ rowptr, int* __restrict__ cursor,
                       int* __restrict__ csr) {
    int i = blockIdx.x * blockDim.x + threadIdx.x;
    if (i >= E + N) return;
    int s, d;
    if (i < E) { s = ei[i]; d = ei[E + i]; }
    else       { s = i - E; d = i - E; }
    int pos = atomicAdd(&cursor[d], 1);
    csr[rowptr[d] + pos] = s;
}

// ---------------------------------------------------------------------------
// Layer-1 aggregation: one wave per dst node, flash online segment-softmax.
// lane owns channels {2*lane, 2*lane+1} (same head h=lane>>4). Atomic-free.
// out = sum(exp(e-m)*h1[src]) / (sum(exp(e-m)) + 1e-16) + b1
// ---------------------------------------------------------------------------
__global__ __launch_bounds__(256) void k_agg1(const int* __restrict__ rowptr,
                                              const int* __restrict__ deg,
                                              const int* __restrict__ csr,
                                              const float* __restrict__ h1,
                                              const float* __restrict__ ssrc,
                                              const float* __restrict__ sdst,
                                              const float* __restrict__ b1,
                                              float* __restrict__ out, int N) {
    int wave = (blockIdx.x * blockDim.x + threadIdx.x) >> 6;
    int lane = threadIdx.x & 63;
    if (wave >= N) return;
    int n = wave;
    int start = rowptr[n], dcnt = deg[n];
    int h = lane >> 4;                       // head of channels 2*lane, 2*lane+1
    float sd = sdst[n * 4 + h];
    float m = -3e38f, l = 0.f;
    float ax = 0.f, ay = 0.f;
    const float2* h1v = (const float2*)h1;
    for (int j = 0; j < dcnt; ++j) {
        int s = csr[start + j];
        float e = ssrc[s * 4 + h] + sd;
        e = e > 0.f ? e : NEG_SLOPE * e;
        float2 v = h1v[(size_t)s * 64 + lane];
        float nm = fmaxf(m, e);
        float sc = __expf(m - nm);
        float p  = __expf(e - nm);
        ax = ax * sc + p * v.x;
        ay = ay * sc + p * v.y;
        l  = l * sc + p;
        m  = nm;
    }
    float inv = 1.f / (l + 1e-16f);
    float2 o = make_float2(ax * inv + b1[2 * lane], ay * inv + b1[2 * lane + 1]);
    ((float2*)out)[(size_t)n * 64 + lane] = o;
}

// ---------------------------------------------------------------------------
// BatchNorm: column stats (two-pass), then apply + ELU in place
// ---------------------------------------------------------------------------
__global__ void k_bnstat(const float* __restrict__ hb, float* __restrict__ bnsum,
                         float* __restrict__ bnsq, int N) {
    int c = threadIdx.x;                      // 128 threads
    float s = 0.f, q = 0.f;
    for (int r = blockIdx.x; r < N; r += gridDim.x) {
        float v = hb[(size_t)r * FH + c];
        s += v;
        q += v * v;
    }
    atomicAdd(&bnsum[c], s);
    atomicAdd(&bnsq[c], q);
}

__global__ void k_bnapply(float4* __restrict__ hb4, const float* __restrict__ bnsum,
                          const float* __restrict__ bnsq, const float* __restrict__ gamma,
                          const float* __restrict__ beta, int total4, float invN) {
    int idx = blockIdx.x * blockDim.x + threadIdx.x;
    if (idx >= total4) return;
    int cb = (idx & 31) * 4;
    float4 v = hb4[idx];
    float r[4] = {v.x, v.y, v.z, v.w};
    #pragma unroll
    for (int j = 0; j < 4; ++j) {
        int c = cb + j;
        float mu  = bnsum[c] * invN;
        float var = bnsq[c] * invN - mu * mu;
        float tv  = (r[j] - mu) * rsqrtf(var + BN_EPS) * gamma[c] + beta[c];
        r[j] = tv > 0.f ? tv : expm1f(tv);    // ELU
    }
    hb4[idx] = make_float4(r[0], r[1], r[2], r[3]);
}

// ---------------------------------------------------------------------------
// Layer 2 linear + scores: one wave per row. h2 = hb @ W2 ([128,2]),
// s_src2 = h2 . a_src2, s_dst2 = h2 . a_dst2
// ---------------------------------------------------------------------------
__global__ __launch_bounds__(256) void k_l2a(const float* __restrict__ hb,
                                             const float* __restrict__ W2,
                                             const float* __restrict__ as2,
                                             const float* __restrict__ ad2,
                                             float* __restrict__ h2,
                                             float* __restrict__ ss2,
                                             float* __restrict__ sd2, int N) {
    int wave = (blockIdx.x * blockDim.x + threadIdx.x) >> 6;
    int lane = threadIdx.x & 63;
    if (wave >= N) return;
    float2 v = ((const float2*)hb)[(size_t)wave * 64 + lane];
    int c0 = 2 * lane, c1 = 2 * lane + 1;
    float d0 = v.x * W2[c0 * 2]     + v.y * W2[c1 * 2];
    float d1 = v.x * W2[c0 * 2 + 1] + v.y * W2[c1 * 2 + 1];
    #pragma unroll
    for (int off = 32; off > 0; off >>= 1) {
        d0 += __shfl_down(d0, off, 64);
        d1 += __shfl_down(d1, off, 64);
    }
    if (lane == 0) {
        h2[wave * 2]     = d0;
        h2[wave * 2 + 1] = d1;
        ss2[wave] = d0 * as2[0] + d1 * as2[1];
        sd2[wave] = d0 * ad2[0] + d1 * ad2[1];
    }
}

// ---------------------------------------------------------------------------
// Layer-2 aggregation: one wave per node, lanes split the edge list,
// per-lane online softmax, butterfly merge. out = agg + b2.
// ---------------------------------------------------------------------------
__global__ __launch_bounds__(256) void k_agg2(const int* __restrict__ rowptr,
                                              const int* __restrict__ deg,
                                              const int* __restrict__ csr,
                                              const float* __restrict__ h2,
                                              const float* __restrict__ ss2,
                                              const float* __restrict__ sd2,
                                              const float* __restrict__ b2,
                                              float* __restrict__ out, int N) {
    int wave = (blockIdx.x * blockDim.x + threadIdx.x) >> 6;
    int lane = threadIdx.x & 63;
    if (wave >= N) return;
    int start = rowptr[wave], dcnt = deg[wave];
    float sdv = sd2[wave];
    float m = -3e38f, l = 0.f, a0 = 0.f, a1 = 0.f;
    for (int j = lane; j < dcnt; j += 64) {
        int s = csr[start + j];
        float e = ss2[s] + sdv;
        e = e > 0.f ? e : NEG_SLOPE * e;
        float2 hv = ((const float2*)h2)[s];
        float nm = fmaxf(m, e);
        float sc = __expf(m - nm);
        float p  = __expf(e - nm);
        a0 = a0 * sc + p * hv.x;
        a1 = a1 * sc + p * hv.y;
        l  = l * sc + p;
        m  = nm;
    }
    #pragma unroll
    for (int off = 32; off > 0; off >>= 1) {
        float mo  = __shfl_xor(m, off, 64);
        float lo  = __shfl_xor(l, off, 64);
        float a0o = __shfl_xor(a0, off, 64);
        float a1o = __shfl_xor(a1, off, 64);
        float nm = fmaxf(m, mo);
        float sc = __expf(m - nm), so = __expf(mo - nm);
        l  = l * sc + lo * so;
        a0 = a0 * sc + a0o * so;
        a1 = a1 * sc + a1o * so;
        m  = nm;
    }
    if (lane == 0) {
        float inv = 1.f / (l + 1e-16f);
        out[wave * 2]     = a0 * inv + b2[0];
        out[wave * 2 + 1] = a1 * inv + b2[1];
    }
}

// ---------------------------------------------------------------------------
extern "C" void kernel_launch(void* const* d_in, const int* in_sizes, int n_in,
                              void* d_out, int out_size, void* d_ws, size_t ws_size,
                              hipStream_t stream) {
    const int N = in_sizes[0] / FH;       // 50000
    const int E = in_sizes[1] / 2;        // 800000
    const int Etot = E + N;

    const float* x     = (const float*)d_in[0];
    const int*   ei    = (const int*)d_in[1];   // int32 (JAX x64 off)
    const float* W1    = (const float*)d_in[2];
    const float* asrc1 = (const float*)d_in[3];
    const float* adst1 = (const float*)d_in[4];
    const float* b1    = (const float*)d_in[5];
    const float* gamma = (const float*)d_in[6];
    const float* beta  = (const float*)d_in[7];
    const float* W2    = (const float*)d_in[8];
    const float* as2   = (const float*)d_in[9];
    const float* ad2   = (const float*)d_in[10];
    const float* b2    = (const float*)d_in[11];
    float* out = (float*)d_out;

    // workspace layout (256B aligned)
    char* ws = (char*)d_ws;
    size_t off = 0;
    auto nxt = [&](size_t bytes) {
        size_t o = off;
        off += (bytes + 255) & ~(size_t)255;
        return o;
    };
    float* h1     = (float*)(ws + nxt((size_t)N * FH * 4));
    float* hb     = (float*)(ws + nxt((size_t)N * FH * 4));
    float* ssrc1  = (float*)(ws + nxt((size_t)N * 4 * 4));
    float* sdst1  = (float*)(ws + nxt((size_t)N * 4 * 4));
    float* h2     = (float*)(ws + nxt((size_t)N * 2 * 4));
    float* ss2    = (float*)(ws + nxt((size_t)N * 4));
    float* sd2    = (float*)(ws + nxt((size_t)N * 4));
    int*   deg    = (int*)(ws + nxt((size_t)N * 4));
    int*   rowptr = (int*)(ws + nxt((size_t)(N + 1) * 4));
    int*   cursor = (int*)(ws + nxt((size_t)N * 4));
    int*   csr    = (int*)(ws + nxt((size_t)Etot * 4));
    float* bnsum  = (float*)(ws + nxt(128 * 4));
    float* bnsq   = (float*)(ws + nxt(128 * 4));

    // zero what we accumulate into (ws is poisoned 0xAA before every call)
    hipMemsetAsync(deg, 0, (size_t)N * 4, stream);
    hipMemsetAsync(cursor, 0, (size_t)N * 4, stream);
    hipMemsetAsync(bnsum, 0, 128 * 4, stream);
    hipMemsetAsync(bnsq, 0, 128 * 4, stream);

    dim3 g1((N + 31) / 32, 2);
    k_gemm1<<<g1, 256, 0, stream>>>(x, W1, h1, N);
    k_scores1<<<(N * 4 + 255) / 256, 256, 0, stream>>>(h1, asrc1, adst1, ssrc1, sdst1, N);
    k_count<<<(Etot + 255) / 256, 256, 0, stream>>>(ei, E, N, deg);
    k_scan<<<1, 1024, 0, stream>>>(deg, rowptr, N);
    k_fill<<<(Etot + 255) / 256, 256, 0, stream>>>(ei, E, N, rowptr, cursor, csr);
    k_agg1<<<(N + 3) / 4, 256, 0, stream>>>(rowptr, deg, csr, h1, ssrc1, sdst1, b1, hb, N);
    k_bnstat<<<256, 128, 0, stream>>>(hb, bnsum, bnsq, N);
    int total4 = N * 32;
    k_bnapply<<<(total4 + 255) / 256, 256, 0, stream>>>((float4*)hb, bnsum, bnsq, gamma, beta,
                                                        total4, 1.0f / (float)N);
    k_l2a<<<(N + 3) / 4, 256, 0, stream>>>(hb, W2, as2, ad2, h2, ss2, sd2, N);
    k_agg2<<<(N + 3) / 4, 256, 0, stream>>>(rowptr, deg, csr, h2, ss2, sd2, b2, out, N);
}

// Round 2
// 427.353 us; speedup vs baseline: 1.2163x; 1.2163x over previous
//
#include <hip/hip_runtime.h>
#include <hip/hip_bf16.h>
#include <math.h>

#define FH 128     // hidden = heads(4) * C(32)
#define NEG_SLOPE 0.2f
#define BN_EPS 1e-5f

// ---------------------------------------------------------------------------
// GEMM1: h1 = x @ W1 [N,128]x[128,128], fused per-(node,head) attention scores.
// tile 64 rows x 64 cols, thread computes 2 rows x 8 cols. grid (ceil(N/64), 2)
// ---------------------------------------------------------------------------
__global__ __launch_bounds__(256) void k_gemm1(
    const float* __restrict__ x, const float* __restrict__ W,
    const float* __restrict__ asrc, const float* __restrict__ adst,
    float* __restrict__ h1, float* __restrict__ ssrc, float* __restrict__ sdst,
    int N)
{
    __shared__ float xs[64][132];    // +4 pad: bank (4r+k)%32 distinct per r
    __shared__ float Ws[128][64];
    const int t = threadIdx.x;
    const int row0 = blockIdx.x * 64;
    const int col0 = blockIdx.y * 64;

    // x tile: 64x128 floats = 2048 float4, 8 per thread, coalesced
    #pragma unroll
    for (int i = 0; i < 8; ++i) {
        int f = (i * 256 + t) * 4;
        int r = f >> 7, c = f & 127;
        float4 v = make_float4(0.f, 0.f, 0.f, 0.f);
        if (row0 + r < N) v = *(const float4*)(x + (size_t)(row0 + r) * FH + c);
        xs[r][c] = v.x; xs[r][c + 1] = v.y; xs[r][c + 2] = v.z; xs[r][c + 3] = v.w;
    }
    // W tile: 128x64 floats = 2048 float4, 8 per thread, coalesced
    #pragma unroll
    for (int i = 0; i < 8; ++i) {
        int f = (i * 256 + t) * 4;
        int k = f >> 6, c = f & 63;
        *(float4*)&Ws[k][c] = *(const float4*)(W + (size_t)k * FH + col0 + c);
    }
    __syncthreads();

    const int r  = t >> 3;           // 0..31 -> rows r and r+32
    const int cq = (t & 7) * 8;      // 0..56
    float accA[8] = {0,0,0,0,0,0,0,0};
    float accB[8] = {0,0,0,0,0,0,0,0};
    #pragma unroll 4
    for (int k = 0; k < 128; ++k) {
        float xa = xs[r][k];
        float xb = xs[r + 32][k];
        float4 w0 = *(const float4*)&Ws[k][cq];
        float4 w1 = *(const float4*)&Ws[k][cq + 4];
        accA[0] = fmaf(xa, w0.x, accA[0]); accA[1] = fmaf(xa, w0.y, accA[1]);
        accA[2] = fmaf(xa, w0.z, accA[2]); accA[3] = fmaf(xa, w0.w, accA[3]);
        accA[4] = fmaf(xa, w1.x, accA[4]); accA[5] = fmaf(xa, w1.y, accA[5]);
        accA[6] = fmaf(xa, w1.z, accA[6]); accA[7] = fmaf(xa, w1.w, accA[7]);
        accB[0] = fmaf(xb, w0.x, accB[0]); accB[1] = fmaf(xb, w0.y, accB[1]);
        accB[2] = fmaf(xb, w0.z, accB[2]); accB[3] = fmaf(xb, w0.w, accB[3]);
        accB[4] = fmaf(xb, w1.x, accB[4]); accB[5] = fmaf(xb, w1.y, accB[5]);
        accB[6] = fmaf(xb, w1.z, accB[6]); accB[7] = fmaf(xb, w1.w, accB[7]);
    }

    // fused scores: this thread's 8 cols lie in one head
    const int hg = (col0 >> 5) + (cq >> 5);    // global head 0..3
    const int cl = cq & 31;
    float4 as0 = *(const float4*)(asrc + hg * 32 + cl);
    float4 as1 = *(const float4*)(asrc + hg * 32 + cl + 4);
    float4 ad0 = *(const float4*)(adst + hg * 32 + cl);
    float4 ad1 = *(const float4*)(adst + hg * 32 + cl + 4);
    float sA = accA[0]*as0.x + accA[1]*as0.y + accA[2]*as0.z + accA[3]*as0.w
             + accA[4]*as1.x + accA[5]*as1.y + accA[6]*as1.z + accA[7]*as1.w;
    float dA = accA[0]*ad0.x + accA[1]*ad0.y + accA[2]*ad0.z + accA[3]*ad0.w
             + accA[4]*ad1.x + accA[5]*ad1.y + accA[6]*ad1.z + accA[7]*ad1.w;
    float sB = accB[0]*as0.x + accB[1]*as0.y + accB[2]*as0.z + accB[3]*as0.w
             + accB[4]*as1.x + accB[5]*as1.y + accB[6]*as1.z + accB[7]*as1.w;
    float dB = accB[0]*ad0.x + accB[1]*ad0.y + accB[2]*ad0.z + accB[3]*ad0.w
             + accB[4]*ad1.x + accB[5]*ad1.y + accB[6]*ad1.z + accB[7]*ad1.w;
    // reduce across the 4 lanes sharing (row, head) — consecutive lanes
    sA += __shfl_xor(sA, 1, 64); sA += __shfl_xor(sA, 2, 64);
    dA += __shfl_xor(dA, 1, 64); dA += __shfl_xor(dA, 2, 64);
    sB += __shfl_xor(sB, 1, 64); sB += __shfl_xor(sB, 2, 64);
    dB += __shfl_xor(dB, 1, 64); dB += __shfl_xor(dB, 2, 64);

    int ra = row0 + r, rb = row0 + r + 32;
    if (ra < N) {
        float* p = h1 + (size_t)ra * FH + col0 + cq;
        *(float4*)p       = make_float4(accA[0], accA[1], accA[2], accA[3]);
        *(float4*)(p + 4) = make_float4(accA[4], accA[5], accA[6], accA[7]);
        if ((t & 3) == 0) { ssrc[ra * 4 + hg] = sA; sdst[ra * 4 + hg] = dA; }
    }
    if (rb < N) {
        float* p = h1 + (size_t)rb * FH + col0 + cq;
        *(float4*)p       = make_float4(accB[0], accB[1], accB[2], accB[3]);
        *(float4*)(p + 4) = make_float4(accB[4], accB[5], accB[6], accB[7]);
        if ((t & 3) == 0) { ssrc[rb * 4 + hg] = sB; sdst[rb * 4 + hg] = dB; }
    }
}

// ---------------------------------------------------------------------------
// CSR build
// ---------------------------------------------------------------------------
__global__ void k_count(const int* __restrict__ ei, int E, int N, int* __restrict__ deg) {
    int i = blockIdx.x * blockDim.x + threadIdx.x;
    if (i >= E + N) return;
    int d = (i < E) ? ei[E + i] : (i - E);
    atomicAdd(&deg[d], 1);
}

// chunked single-block scan: thread t serially scans its own chunk, one
// 1024-wide block scan of the chunk totals, then writes back. ~2 passes total.
__global__ __launch_bounds__(1024) void k_scan(const int* __restrict__ deg,
                                               int* __restrict__ rowptr, int N) {
    __shared__ int buf[1024];
    int t = threadIdx.x;
    int chunk = (N + 1023) >> 10;
    int b = t * chunk; if (b > N) b = N;
    int e = b + chunk; if (e > N) e = N;
    int s = 0;
    for (int i = b; i < e; ++i) s += deg[i];
    buf[t] = s;
    __syncthreads();
    for (int off = 1; off < 1024; off <<= 1) {
        int o = (t >= off) ? buf[t - off] : 0;
        __syncthreads();
        buf[t] += o;
        __syncthreads();
    }
    int carry = buf[t] - s;      // exclusive prefix of this chunk
    for (int i = b; i < e; ++i) { rowptr[i] = carry; carry += deg[i]; }
    if (b < N && e == N) rowptr[N] = carry;
}

__global__ void k_fill(const int* __restrict__ ei, int E, int N,
                       const int* __restrict__ rowptr, int* __restrict__ cursor,
                       int* __restrict__ csr) {
    int i = blockIdx.x * blockDim.x + threadIdx.x;
    if (i >= E + N) return;
    int s, d;
    if (i < E) { s = ei[i]; d = ei[E + i]; }
    else       { s = i - E; d = i - E; }
    int pos = atomicAdd(&cursor[d], 1);
    csr[rowptr[d] + pos] = s;
}

// ---------------------------------------------------------------------------
// Layer-1 aggregation, one wave per dst node, two-pass (no serial softmax chain):
// pass 1: lanes split edges, per-head (m,l) via butterfly (csr+ssrc only, L2-hot)
// pass 2: dependency-free gather-FMA over h1 rows (the 208MB fabric stream)
// ---------------------------------------------------------------------------
__global__ __launch_bounds__(256) void k_agg1(
    const int* __restrict__ rowptr, const int* __restrict__ csr,
    const float* __restrict__ h1, const float* __restrict__ ssrc,
    const float* __restrict__ sdst, const float* __restrict__ b1,
    float* __restrict__ out, int N)
{
    int n = (blockIdx.x * blockDim.x + threadIdx.x) >> 6;
    int lane = threadIdx.x & 63;
    if (n >= N) return;
    int start = rowptr[n];
    int dcnt  = rowptr[n + 1] - start;

    float4 sd4 = *(const float4*)(sdst + n * 4);
    float mx = -3e38f, my = -3e38f, mz = -3e38f, mw = -3e38f;
    float lx = 0.f, ly = 0.f, lz = 0.f, lw = 0.f;
    for (int j = lane; j < dcnt; j += 64) {
        int s = csr[start + j];
        float4 sv = *(const float4*)(ssrc + s * 4);
        float ex = sv.x + sd4.x; ex = ex > 0.f ? ex : NEG_SLOPE * ex;
        float ey = sv.y + sd4.y; ey = ey > 0.f ? ey : NEG_SLOPE * ey;
        float ez = sv.z + sd4.z; ez = ez > 0.f ? ez : NEG_SLOPE * ez;
        float ew = sv.w + sd4.w; ew = ew > 0.f ? ew : NEG_SLOPE * ew;
        float nm;
        nm = fmaxf(mx, ex); lx = lx * __expf(mx - nm) + __expf(ex - nm); mx = nm;
        nm = fmaxf(my, ey); ly = ly * __expf(my - nm) + __expf(ey - nm); my = nm;
        nm = fmaxf(mz, ez); lz = lz * __expf(mz - nm) + __expf(ez - nm); mz = nm;
        nm = fmaxf(mw, ew); lw = lw * __expf(mw - nm) + __expf(ew - nm); mw = nm;
    }
    float pmx = mx, pmy = my, pmz = mz, pmw = mw;
    #pragma unroll
    for (int off = 32; off; off >>= 1) {
        mx = fmaxf(mx, __shfl_xor(mx, off, 64));
        my = fmaxf(my, __shfl_xor(my, off, 64));
        mz = fmaxf(mz, __shfl_xor(mz, off, 64));
        mw = fmaxf(mw, __shfl_xor(mw, off, 64));
    }
    lx *= __expf(pmx - mx); ly *= __expf(pmy - my);
    lz *= __expf(pmz - mz); lw *= __expf(pmw - mw);
    #pragma unroll
    for (int off = 32; off; off >>= 1) {
        lx += __shfl_xor(lx, off, 64);
        ly += __shfl_xor(ly, off, 64);
        lz += __shfl_xor(lz, off, 64);
        lw += __shfl_xor(lw, off, 64);
    }

    int h = lane >> 4;                 // head of channels {2*lane, 2*lane+1}
    float Mh  = h == 0 ? mx : h == 1 ? my : h == 2 ? mz : mw;
    float Lh  = h == 0 ? lx : h == 1 ? ly : h == 2 ? lz : lw;
    float sdh = h == 0 ? sd4.x : h == 1 ? sd4.y : h == 2 ? sd4.z : sd4.w;
    float invl = 1.f / (Lh + 1e-16f);

    float ax = 0.f, ay = 0.f;
    const float2* h1v = (const float2*)h1;
    #pragma unroll 4
    for (int j = 0; j < dcnt; ++j) {
        int s = csr[start + j];
        float e = ssrc[s * 4 + h] + sdh;
        e = e > 0.f ? e : NEG_SLOPE * e;
        float p = __expf(e - Mh);
        float2 v = h1v[(size_t)s * 64 + lane];
        ax = fmaf(p, v.x, ax);
        ay = fmaf(p, v.y, ay);
    }
    float2 o;
    o.x = fmaf(ax, invl, b1[2 * lane]);
    o.y = fmaf(ay, invl, b1[2 * lane + 1]);
    ((float2*)out)[(size_t)n * 64 + lane] = o;
}

// ---------------------------------------------------------------------------
// BN column stats: 512 blocks x 256 thr, float4, LDS tree + 1 atomic round
// ---------------------------------------------------------------------------
__global__ __launch_bounds__(256) void k_bnstat(const float4* __restrict__ hb4,
                                                float* __restrict__ bnsum,
                                                float* __restrict__ bnsq, int N) {
    __shared__ float rs[8][128];
    __shared__ float rq[8][128];
    int t = threadIdx.x;
    int rg = t >> 5, c4 = t & 31;
    float sx = 0, sy = 0, sz = 0, sw = 0, qx = 0, qy = 0, qz = 0, qw = 0;
    for (int r = blockIdx.x * 8 + rg; r < N; r += gridDim.x * 8) {
        float4 v = hb4[(size_t)r * 32 + c4];
        sx += v.x; sy += v.y; sz += v.z; sw += v.w;
        qx = fmaf(v.x, v.x, qx); qy = fmaf(v.y, v.y, qy);
        qz = fmaf(v.z, v.z, qz); qw = fmaf(v.w, v.w, qw);
    }
    int c = c4 * 4;
    rs[rg][c] = sx; rs[rg][c+1] = sy; rs[rg][c+2] = sz; rs[rg][c+3] = sw;
    rq[rg][c] = qx; rq[rg][c+1] = qy; rq[rg][c+2] = qz; rq[rg][c+3] = qw;
    __syncthreads();
    for (int k = 4; k; k >>= 1) {
        if (rg < k) {
            rs[rg][c]   += rs[rg+k][c];   rs[rg][c+1] += rs[rg+k][c+1];
            rs[rg][c+2] += rs[rg+k][c+2]; rs[rg][c+3] += rs[rg+k][c+3];
            rq[rg][c]   += rq[rg+k][c];   rq[rg][c+1] += rq[rg+k][c+1];
            rq[rg][c+2] += rq[rg+k][c+2]; rq[rg][c+3] += rq[rg+k][c+3];
        }
        __syncthreads();
    }
    if (t < 32) {
        int cc = t * 4;
        atomicAdd(&bnsum[cc],   rs[0][cc]);   atomicAdd(&bnsum[cc+1], rs[0][cc+1]);
        atomicAdd(&bnsum[cc+2], rs[0][cc+2]); atomicAdd(&bnsum[cc+3], rs[0][cc+3]);
        atomicAdd(&bnsq[cc],    rq[0][cc]);   atomicAdd(&bnsq[cc+1],  rq[0][cc+1]);
        atomicAdd(&bnsq[cc+2],  rq[0][cc+2]); atomicAdd(&bnsq[cc+3],  rq[0][cc+3]);
    }
}

__global__ void k_bnfin(const float* __restrict__ bnsum, const float* __restrict__ bnsq,
                        const float* __restrict__ gamma, const float* __restrict__ beta,
                        float* __restrict__ scale, float* __restrict__ shift, float invN) {
    int c = threadIdx.x;   // 128
    float mu  = bnsum[c] * invN;
    float var = bnsq[c] * invN - mu * mu;
    float sc  = rsqrtf(var + BN_EPS) * gamma[c];
    scale[c] = sc;
    shift[c] = beta[c] - mu * sc;
}

// ---------------------------------------------------------------------------
// Fused BN-apply + ELU + layer-2 linear + layer-2 scores.
// Never materializes the normalized matrix. Packs (h2x,h2y,ss2,sd2) per node.
// block 256 = 8 rows x 32 lanes x float4
// ---------------------------------------------------------------------------
__global__ __launch_bounds__(256) void k_bn2(const float4* __restrict__ hb4,
                                             const float* __restrict__ scale,
                                             const float* __restrict__ shift,
                                             const float* __restrict__ W2,
                                             const float* __restrict__ as2,
                                             const float* __restrict__ ad2,
                                             float4* __restrict__ node2, int N) {
    int t = threadIdx.x;
    int rl = t >> 5, c4 = t & 31;
    int r = blockIdx.x * 8 + rl;
    if (r >= N) return;
    float4 v = hb4[(size_t)r * 32 + c4];
    int c = c4 * 4;
    float t0 = fmaf(v.x, scale[c],     shift[c]);
    float t1 = fmaf(v.y, scale[c + 1], shift[c + 1]);
    float t2 = fmaf(v.z, scale[c + 2], shift[c + 2]);
    float t3 = fmaf(v.w, scale[c + 3], shift[c + 3]);
    t0 = t0 > 0.f ? t0 : expm1f(t0);
    t1 = t1 > 0.f ? t1 : expm1f(t1);
    t2 = t2 > 0.f ? t2 : expm1f(t2);
    t3 = t3 > 0.f ? t3 : expm1f(t3);
    float d0 = t0 * W2[c * 2]       + t1 * W2[(c + 1) * 2]
             + t2 * W2[(c + 2) * 2] + t3 * W2[(c + 3) * 2];
    float d1 = t0 * W2[c * 2 + 1]       + t1 * W2[(c + 1) * 2 + 1]
             + t2 * W2[(c + 2) * 2 + 1] + t3 * W2[(c + 3) * 2 + 1];
    #pragma unroll
    for (int off = 16; off; off >>= 1) {
        d0 += __shfl_xor(d0, off, 64);
        d1 += __shfl_xor(d1, off, 64);
    }
    if (c4 == 0) {
        float4 o;
        o.x = d0; o.y = d1;
        o.z = d0 * as2[0] + d1 * as2[1];
        o.w = d0 * ad2[0] + d1 * ad2[1];
        node2[r] = o;
    }
}

// ---------------------------------------------------------------------------
// Layer-2 aggregation: 16 lanes per node (avg degree ~17), single float4
// gather per edge, width-16 butterfly softmax merge.
// ---------------------------------------------------------------------------
__global__ __launch_bounds__(256) void k_agg2(const int* __restrict__ rowptr,
                                              const int* __restrict__ csr,
                                              const float4* __restrict__ node2,
                                              const float* __restrict__ b2,
                                              float* __restrict__ out, int N) {
    int gid = blockIdx.x * blockDim.x + threadIdx.x;
    int n = gid >> 4;
    int ln = gid & 15;
    if (n >= N) return;
    int start = rowptr[n];
    int dcnt  = rowptr[n + 1] - start;
    float sdv = node2[n].w;
    float m = -3e38f, l = 0.f, a0 = 0.f, a1 = 0.f;
    for (int j = ln; j < dcnt; j += 16) {
        int s = csr[start + j];
        float4 hv = node2[s];
        float e = hv.z + sdv;
        e = e > 0.f ? e : NEG_SLOPE * e;
        float nm = fmaxf(m, e);
        float sc = __expf(m - nm);
        float p  = __expf(e - nm);
        a0 = a0 * sc + p * hv.x;
        a1 = a1 * sc + p * hv.y;
        l  = l * sc + p;
        m  = nm;
    }
    #pragma unroll
    for (int off = 8; off; off >>= 1) {
        float mo  = __shfl_xor(m, off, 64);
        float lo  = __shfl_xor(l, off, 64);
        float a0o = __shfl_xor(a0, off, 64);
        float a1o = __shfl_xor(a1, off, 64);
        float nm = fmaxf(m, mo);
        float sc = __expf(m - nm), so = __expf(mo - nm);
        l  = l * sc + lo * so;
        a0 = a0 * sc + a0o * so;
        a1 = a1 * sc + a1o * so;
        m  = nm;
    }
    if (ln == 0) {
        float inv = 1.f / (l + 1e-16f);
        float2 o;
        o.x = fmaf(a0, inv, b2[0]);
        o.y = fmaf(a1, inv, b2[1]);
        ((float2*)out)[n] = o;
    }
}

// ---------------------------------------------------------------------------
extern "C" void kernel_launch(void* const* d_in, const int* in_sizes, int n_in,
                              void* d_out, int out_size, void* d_ws, size_t ws_size,
                              hipStream_t stream) {
    const int N = in_sizes[0] / FH;       // 50000
    const int E = in_sizes[1] / 2;        // 800000
    const int Etot = E + N;

    const float* x     = (const float*)d_in[0];
    const int*   ei    = (const int*)d_in[1];
    const float* W1    = (const float*)d_in[2];
    const float* asrc1 = (const float*)d_in[3];
    const float* adst1 = (const float*)d_in[4];
    const float* b1    = (const float*)d_in[5];
    const float* gamma = (const float*)d_in[6];
    const float* beta  = (const float*)d_in[7];
    const float* W2    = (const float*)d_in[8];
    const float* as2   = (const float*)d_in[9];
    const float* ad2   = (const float*)d_in[10];
    const float* b2    = (const float*)d_in[11];
    float* out = (float*)d_out;

    char* ws = (char*)d_ws;
    size_t off = 0;
    auto nxt = [&](size_t bytes) {
        size_t o = off;
        off += (bytes + 255) & ~(size_t)255;
        return o;
    };
    float* h1      = (float*)(ws + nxt((size_t)N * FH * 4));
    float* hb      = (float*)(ws + nxt((size_t)N * FH * 4));
    float* ssrc1   = (float*)(ws + nxt((size_t)N * 4 * 4));
    float* sdst1   = (float*)(ws + nxt((size_t)N * 4 * 4));
    float* node2   = (float*)(ws + nxt((size_t)N * 4 * 4));
    int*   deg     = (int*)(ws + nxt((size_t)N * 4));
    int*   rowptr  = (int*)(ws + nxt((size_t)(N + 1) * 4));
    int*   cursor  = (int*)(ws + nxt((size_t)N * 4));
    int*   csr     = (int*)(ws + nxt((size_t)Etot * 4));
    float* bnsum   = (float*)(ws + nxt(128 * 4));
    float* bnsq    = (float*)(ws + nxt(128 * 4));
    float* bnscale = (float*)(ws + nxt(128 * 4));
    float* bnshift = (float*)(ws + nxt(128 * 4));

    hipMemsetAsync(deg, 0, (size_t)N * 4, stream);
    hipMemsetAsync(cursor, 0, (size_t)N * 4, stream);
    hipMemsetAsync(bnsum, 0, 128 * 4, stream);
    hipMemsetAsync(bnsq, 0, 128 * 4, stream);

    dim3 g1((N + 63) / 64, 2);
    k_gemm1<<<g1, 256, 0, stream>>>(x, W1, asrc1, adst1, h1, ssrc1, sdst1, N);
    k_count<<<(Etot + 255) / 256, 256, 0, stream>>>(ei, E, N, deg);
    k_scan<<<1, 1024, 0, stream>>>(deg, rowptr, N);
    k_fill<<<(Etot + 255) / 256, 256, 0, stream>>>(ei, E, N, rowptr, cursor, csr);
    k_agg1<<<(N + 3) / 4, 256, 0, stream>>>(rowptr, csr, h1, ssrc1, sdst1, b1, hb, N);
    k_bnstat<<<512, 256, 0, stream>>>((const float4*)hb, bnsum, bnsq, N);
    k_bnfin<<<1, 128, 0, stream>>>(bnsum, bnsq, gamma, beta, bnscale, bnshift,
                                   1.0f / (float)N);
    k_bn2<<<(N + 7) / 8, 256, 0, stream>>>((const float4*)hb, bnscale, bnshift,
                                           W2, as2, ad2, (float4*)node2, N);
    k_agg2<<<(N * 16 + 255) / 256, 256, 0, stream>>>(rowptr, csr, (const float4*)node2,
                                                     b2, out, N);
}

// Round 7
// 350.626 us; speedup vs baseline: 1.4825x; 1.2188x over previous
//
#include <hip/hip_runtime.h>
#include <hip/hip_bf16.h>
#include <math.h>

#define FH 128     // hidden = heads(4) * C(32)
#define NEG_SLOPE 0.2f
#define BN_EPS 1e-5f

// ---------------------------------------------------------------------------
// GEMM1: h1 = x @ W1 [N,128]x[128,128], fused per-(node,head) attention scores.
// tile 64 rows x 64 cols, thread computes 2 rows x 8 cols. grid (ceil(N/64), 2)
// ---------------------------------------------------------------------------
__global__ __launch_bounds__(256) void k_gemm1(
    const float* __restrict__ x, const float* __restrict__ W,
    const float* __restrict__ asrc, const float* __restrict__ adst,
    float* __restrict__ h1, float* __restrict__ ssrc, float* __restrict__ sdst,
    int N)
{
    __shared__ float xs[64][132];    // +4 pad: bank (4r+k)%32 distinct per r
    __shared__ float Ws[128][64];
    const int t = threadIdx.x;
    const int row0 = blockIdx.x * 64;
    const int col0 = blockIdx.y * 64;

    #pragma unroll
    for (int i = 0; i < 8; ++i) {
        int f = (i * 256 + t) * 4;
        int r = f >> 7, c = f & 127;
        float4 v = make_float4(0.f, 0.f, 0.f, 0.f);
        if (row0 + r < N) v = *(const float4*)(x + (size_t)(row0 + r) * FH + c);
        xs[r][c] = v.x; xs[r][c + 1] = v.y; xs[r][c + 2] = v.z; xs[r][c + 3] = v.w;
    }
    #pragma unroll
    for (int i = 0; i < 8; ++i) {
        int f = (i * 256 + t) * 4;
        int k = f >> 6, c = f & 63;
        *(float4*)&Ws[k][c] = *(const float4*)(W + (size_t)k * FH + col0 + c);
    }
    __syncthreads();

    const int r  = t >> 3;           // 0..31 -> rows r and r+32
    const int cq = (t & 7) * 8;      // 0..56
    float accA[8] = {0,0,0,0,0,0,0,0};
    float accB[8] = {0,0,0,0,0,0,0,0};
    #pragma unroll 4
    for (int k = 0; k < 128; ++k) {
        float xa = xs[r][k];
        float xb = xs[r + 32][k];
        float4 w0 = *(const float4*)&Ws[k][cq];
        float4 w1 = *(const float4*)&Ws[k][cq + 4];
        accA[0] = fmaf(xa, w0.x, accA[0]); accA[1] = fmaf(xa, w0.y, accA[1]);
        accA[2] = fmaf(xa, w0.z, accA[2]); accA[3] = fmaf(xa, w0.w, accA[3]);
        accA[4] = fmaf(xa, w1.x, accA[4]); accA[5] = fmaf(xa, w1.y, accA[5]);
        accA[6] = fmaf(xa, w1.z, accA[6]); accA[7] = fmaf(xa, w1.w, accA[7]);
        accB[0] = fmaf(xb, w0.x, accB[0]); accB[1] = fmaf(xb, w0.y, accB[1]);
        accB[2] = fmaf(xb, w0.z, accB[2]); accB[3] = fmaf(xb, w0.w, accB[3]);
        accB[4] = fmaf(xb, w1.x, accB[4]); accB[5] = fmaf(xb, w1.y, accB[5]);
        accB[6] = fmaf(xb, w1.z, accB[6]); accB[7] = fmaf(xb, w1.w, accB[7]);
    }

    const int hg = (col0 >> 5) + (cq >> 5);    // global head 0..3
    const int cl = cq & 31;
    float4 as0 = *(const float4*)(asrc + hg * 32 + cl);
    float4 as1 = *(const float4*)(asrc + hg * 32 + cl + 4);
    float4 ad0 = *(const float4*)(adst + hg * 32 + cl);
    float4 ad1 = *(const float4*)(adst + hg * 32 + cl + 4);
    float sA = accA[0]*as0.x + accA[1]*as0.y + accA[2]*as0.z + accA[3]*as0.w
             + accA[4]*as1.x + accA[5]*as1.y + accA[6]*as1.z + accA[7]*as1.w;
    float dA = accA[0]*ad0.x + accA[1]*ad0.y + accA[2]*ad0.z + accA[3]*ad0.w
             + accA[4]*ad1.x + accA[5]*ad1.y + accA[6]*ad1.z + accA[7]*ad1.w;
    float sB = accB[0]*as0.x + accB[1]*as0.y + accB[2]*as0.z + accB[3]*as0.w
             + accB[4]*as1.x + accB[5]*as1.y + accB[6]*as1.z + accB[7]*as1.w;
    float dB = accB[0]*ad0.x + accB[1]*ad0.y + accB[2]*ad0.z + accB[3]*ad0.w
             + accB[4]*ad1.x + accB[5]*ad1.y + accB[6]*ad1.z + accB[7]*ad1.w;
    sA += __shfl_xor(sA, 1, 64); sA += __shfl_xor(sA, 2, 64);
    dA += __shfl_xor(dA, 1, 64); dA += __shfl_xor(dA, 2, 64);
    sB += __shfl_xor(sB, 1, 64); sB += __shfl_xor(sB, 2, 64);
    dB += __shfl_xor(dB, 1, 64); dB += __shfl_xor(dB, 2, 64);

    int ra = row0 + r, rb = row0 + r + 32;
    if (ra < N) {
        float* p = h1 + (size_t)ra * FH + col0 + cq;
        *(float4*)p       = make_float4(accA[0], accA[1], accA[2], accA[3]);
        *(float4*)(p + 4) = make_float4(accA[4], accA[5], accA[6], accA[7]);
        if ((t & 3) == 0) { ssrc[ra * 4 + hg] = sA; sdst[ra * 4 + hg] = dA; }
    }
    if (rb < N) {
        float* p = h1 + (size_t)rb * FH + col0 + cq;
        *(float4*)p       = make_float4(accB[0], accB[1], accB[2], accB[3]);
        *(float4*)(p + 4) = make_float4(accB[4], accB[5], accB[6], accB[7]);
        if ((t & 3) == 0) { ssrc[rb * 4 + hg] = sB; sdst[rb * 4 + hg] = dB; }
    }
}

// ---------------------------------------------------------------------------
// CSR build
// ---------------------------------------------------------------------------
__global__ void k_count(const int* __restrict__ ei, int E, int N, int* __restrict__ deg) {
    int i = blockIdx.x * blockDim.x + threadIdx.x;
    if (i >= E + N) return;
    int d = (i < E) ? ei[E + i] : (i - E);
    atomicAdd(&deg[d], 1);
}

// hierarchical scan, stage 1: each 1024-block scans its tile (wave shuffle +
// LDS wave-sum scan), writes block-local exclusive prefix + block total
__global__ __launch_bounds__(1024) void k_scan1(const int* __restrict__ deg,
                                                int* __restrict__ rowptr,
                                                int* __restrict__ blksum, int N) {
    int t = threadIdx.x;
    int i = blockIdx.x * 1024 + t;
    int v = (i < N) ? deg[i] : 0;
    int lane = t & 63, w = t >> 6;
    int incl = v;
    #pragma unroll
    for (int off = 1; off < 64; off <<= 1) {
        int tmp = __shfl_up(incl, off, 64);
        if (lane >= off) incl += tmp;
    }
    __shared__ int wsum[16];
    if (lane == 63) wsum[w] = incl;
    __syncthreads();
    if (t == 0) {
        int s = 0;
        for (int k = 0; k < 16; ++k) { int x = wsum[k]; wsum[k] = s; s += x; }
    }
    __syncthreads();
    int excl = incl - v + wsum[w];
    if (i < N) rowptr[i] = excl;
    if (t == 1023) blksum[blockIdx.x] = excl + v;
}

// stage 2: single block scans the (<=1024) block totals -> exclusive blkoff,
// plus grand total at blkoff[nblk]
__global__ __launch_bounds__(1024) void k_scan2(const int* __restrict__ blksum,
                                                int* __restrict__ blkoff, int nblk) {
    int t = threadIdx.x;
    int v = (t < nblk) ? blksum[t] : 0;
    int lane = t & 63, w = t >> 6;
    int incl = v;
    #pragma unroll
    for (int off = 1; off < 64; off <<= 1) {
        int tmp = __shfl_up(incl, off, 64);
        if (lane >= off) incl += tmp;
    }
    __shared__ int wsum[16];
    if (lane == 63) wsum[w] = incl;
    __syncthreads();
    if (t == 0) {
        int s = 0;
        for (int k = 0; k < 16; ++k) { int x = wsum[k]; wsum[k] = s; s += x; }
    }
    __syncthreads();
    int excl = incl - v + wsum[w];
    if (t < nblk) blkoff[t] = excl;
    if (t == nblk - 1) blkoff[nblk] = excl + v;
}

// stage 3: add block offsets; rowptr[N] = total
__global__ void k_scan3(int* __restrict__ rowptr, const int* __restrict__ blkoff, int N) {
    int i = blockIdx.x * blockDim.x + threadIdx.x;
    if (i > N) return;
    if (i == N) rowptr[N] = blkoff[(N + 1023) >> 10];
    else        rowptr[i] += blkoff[i >> 10];
}

// fill: slot index via atomicSub on deg (deg dead after scan)
__global__ void k_fill(const int* __restrict__ ei, int E, int N,
                       const int* __restrict__ rowptr, int* __restrict__ deg,
                       int* __restrict__ csr) {
    int i = blockIdx.x * blockDim.x + threadIdx.x;
    if (i >= E + N) return;
    int s, d;
    if (i < E) { s = ei[i]; d = ei[E + i]; }
    else       { s = i - E; d = i - E; }
    int pos = atomicSub(&deg[d], 1) - 1;
    csr[rowptr[d] + pos] = s;
}

// ---------------------------------------------------------------------------
// Layer-1 aggregation, one wave per dst node, two-pass (no serial softmax chain)
// ---------------------------------------------------------------------------
__global__ __launch_bounds__(256) void k_agg1(
    const int* __restrict__ rowptr, const int* __restrict__ csr,
    const float* __restrict__ h1, const float* __restrict__ ssrc,
    const float* __restrict__ sdst, const float* __restrict__ b1,
    float* __restrict__ out, int N)
{
    int n = (blockIdx.x * blockDim.x + threadIdx.x) >> 6;
    int lane = threadIdx.x & 63;
    if (n >= N) return;
    int start = rowptr[n];
    int dcnt  = rowptr[n + 1] - start;

    float4 sd4 = *(const float4*)(sdst + n * 4);
    float mx = -3e38f, my = -3e38f, mz = -3e38f, mw = -3e38f;
    float lx = 0.f, ly = 0.f, lz = 0.f, lw = 0.f;
    for (int j = lane; j < dcnt; j += 64) {
        int s = csr[start + j];
        float4 sv = *(const float4*)(ssrc + s * 4);
        float ex = sv.x + sd4.x; ex = ex > 0.f ? ex : NEG_SLOPE * ex;
        float ey = sv.y + sd4.y; ey = ey > 0.f ? ey : NEG_SLOPE * ey;
        float ez = sv.z + sd4.z; ez = ez > 0.f ? ez : NEG_SLOPE * ez;
        float ew = sv.w + sd4.w; ew = ew > 0.f ? ew : NEG_SLOPE * ew;
        float nm;
        nm = fmaxf(mx, ex); lx = lx * __expf(mx - nm) + __expf(ex - nm); mx = nm;
        nm = fmaxf(my, ey); ly = ly * __expf(my - nm) + __expf(ey - nm); my = nm;
        nm = fmaxf(mz, ez); lz = lz * __expf(mz - nm) + __expf(ez - nm); mz = nm;
        nm = fmaxf(mw, ew); lw = lw * __expf(mw - nm) + __expf(ew - nm); mw = nm;
    }
    float pmx = mx, pmy = my, pmz = mz, pmw = mw;
    #pragma unroll
    for (int off = 32; off; off >>= 1) {
        mx = fmaxf(mx, __shfl_xor(mx, off, 64));
        my = fmaxf(my, __shfl_xor(my, off, 64));
        mz = fmaxf(mz, __shfl_xor(mz, off, 64));
        mw = fmaxf(mw, __shfl_xor(mw, off, 64));
    }
    lx *= __expf(pmx - mx); ly *= __expf(pmy - my);
    lz *= __expf(pmz - mz); lw *= __expf(pmw - mw);
    #pragma unroll
    for (int off = 32; off; off >>= 1) {
        lx += __shfl_xor(lx, off, 64);
        ly += __shfl_xor(ly, off, 64);
        lz += __shfl_xor(lz, off, 64);
        lw += __shfl_xor(lw, off, 64);
    }

    int h = lane >> 4;
    float Mh  = h == 0 ? mx : h == 1 ? my : h == 2 ? mz : mw;
    float Lh  = h == 0 ? lx : h == 1 ? ly : h == 2 ? lz : lw;
    float sdh = h == 0 ? sd4.x : h == 1 ? sd4.y : h == 2 ? sd4.z : sd4.w;
    float invl = 1.f / (Lh + 1e-16f);

    float ax = 0.f, ay = 0.f;
    const float2* h1v = (const float2*)h1;
    #pragma unroll 4
    for (int j = 0; j < dcnt; ++j) {
        int s = csr[start + j];
        float e = ssrc[s * 4 + h] + sdh;
        e = e > 0.f ? e : NEG_SLOPE * e;
        float p = __expf(e - Mh);
        float2 v = h1v[(size_t)s * 64 + lane];
        ax = fmaf(p, v.x, ax);
        ay = fmaf(p, v.y, ay);
    }
    float2 o;
    o.x = fmaf(ax, invl, b1[2 * lane]);
    o.y = fmaf(ay, invl, b1[2 * lane + 1]);
    ((float2*)out)[(size_t)n * 64 + lane] = o;
}

// ---------------------------------------------------------------------------
// BN column stats: 512 blocks x 256 thr, float4, LDS tree + 1 atomic round
// ---------------------------------------------------------------------------
__global__ __launch_bounds__(256) void k_bnstat(const float4* __restrict__ hb4,
                                                float* __restrict__ bnsum,
                                                float* __restrict__ bnsq, int N) {
    __shared__ float rs[8][128];
    __shared__ float rq[8][128];
    int t = threadIdx.x;
    int rg = t >> 5, c4 = t & 31;
    float sx = 0, sy = 0, sz = 0, sw = 0, qx = 0, qy = 0, qz = 0, qw = 0;
    for (int r = blockIdx.x * 8 + rg; r < N; r += gridDim.x * 8) {
        float4 v = hb4[(size_t)r * 32 + c4];
        sx += v.x; sy += v.y; sz += v.z; sw += v.w;
        qx = fmaf(v.x, v.x, qx); qy = fmaf(v.y, v.y, qy);
        qz = fmaf(v.z, v.z, qz); qw = fmaf(v.w, v.w, qw);
    }
    int c = c4 * 4;
    rs[rg][c] = sx; rs[rg][c+1] = sy; rs[rg][c+2] = sz; rs[rg][c+3] = sw;
    rq[rg][c] = qx; rq[rg][c+1] = qy; rq[rg][c+2] = qz; rq[rg][c+3] = qw;
    __syncthreads();
    for (int k = 4; k; k >>= 1) {
        if (rg < k) {
            rs[rg][c]   += rs[rg+k][c];   rs[rg][c+1] += rs[rg+k][c+1];
            rs[rg][c+2] += rs[rg+k][c+2]; rs[rg][c+3] += rs[rg+k][c+3];
            rq[rg][c]   += rq[rg+k][c];   rq[rg][c+1] += rq[rg+k][c+1];
            rq[rg][c+2] += rq[rg+k][c+2]; rq[rg][c+3] += rq[rg+k][c+3];
        }
        __syncthreads();
    }
    if (t < 32) {
        int cc = t * 4;
        atomicAdd(&bnsum[cc],   rs[0][cc]);   atomicAdd(&bnsum[cc+1], rs[0][cc+1]);
        atomicAdd(&bnsum[cc+2], rs[0][cc+2]); atomicAdd(&bnsum[cc+3], rs[0][cc+3]);
        atomicAdd(&bnsq[cc],    rq[0][cc]);   atomicAdd(&bnsq[cc+1],  rq[0][cc+1]);
        atomicAdd(&bnsq[cc+2],  rq[0][cc+2]); atomicAdd(&bnsq[cc+3],  rq[0][cc+3]);
    }
}

// ---------------------------------------------------------------------------
// Fused BN-apply + ELU + layer-2 linear + scores (BN scale/shift computed
// inline from bnsum/bnsq — L2-hot). Packs (h2x,h2y,ss2,sd2) per node.
// ---------------------------------------------------------------------------
__global__ __launch_bounds__(256) void k_bn2(const float4* __restrict__ hb4,
                                             const float* __restrict__ bnsum,
                                             const float* __restrict__ bnsq,
                                             const float* __restrict__ gamma,
                                             const float* __restrict__ beta,
                                             const float* __restrict__ W2,
                                             const float* __restrict__ as2,
                                             const float* __restrict__ ad2,
                                             float4* __restrict__ node2,
                                             int N, float invN) {
    int t = threadIdx.x;
    int rl = t >> 5, c4 = t & 31;
    int r = blockIdx.x * 8 + rl;
    if (r >= N) return;
    int c = c4 * 4;
    float4 s4 = *(const float4*)(bnsum + c);
    float4 q4 = *(const float4*)(bnsq + c);
    float4 g4 = *(const float4*)(gamma + c);
    float4 be4 = *(const float4*)(beta + c);
    float mu0 = s4.x * invN, mu1 = s4.y * invN, mu2 = s4.z * invN, mu3 = s4.w * invN;
    float sc0 = rsqrtf(q4.x * invN - mu0 * mu0 + BN_EPS) * g4.x;
    float sc1 = rsqrtf(q4.y * invN - mu1 * mu1 + BN_EPS) * g4.y;
    float sc2 = rsqrtf(q4.z * invN - mu2 * mu2 + BN_EPS) * g4.z;
    float sc3 = rsqrtf(q4.w * invN - mu3 * mu3 + BN_EPS) * g4.w;
    float sh0 = be4.x - mu0 * sc0, sh1 = be4.y - mu1 * sc1;
    float sh2 = be4.z - mu2 * sc2, sh3 = be4.w - mu3 * sc3;

    float4 v = hb4[(size_t)r * 32 + c4];
    float t0 = fmaf(v.x, sc0, sh0);
    float t1 = fmaf(v.y, sc1, sh1);
    float t2 = fmaf(v.z, sc2, sh2);
    float t3 = fmaf(v.w, sc3, sh3);
    t0 = t0 > 0.f ? t0 : expm1f(t0);
    t1 = t1 > 0.f ? t1 : expm1f(t1);
    t2 = t2 > 0.f ? t2 : expm1f(t2);
    t3 = t3 > 0.f ? t3 : expm1f(t3);
    float d0 = t0 * W2[c * 2]       + t1 * W2[(c + 1) * 2]
             + t2 * W2[(c + 2) * 2] + t3 * W2[(c + 3) * 2];
    float d1 = t0 * W2[c * 2 + 1]       + t1 * W2[(c + 1) * 2 + 1]
             + t2 * W2[(c + 2) * 2 + 1] + t3 * W2[(c + 3) * 2 + 1];
    #pragma unroll
    for (int off = 16; off; off >>= 1) {
        d0 += __shfl_xor(d0, off, 64);
        d1 += __shfl_xor(d1, off, 64);
    }
    if (c4 == 0) {
        float4 o;
        o.x = d0; o.y = d1;
        o.z = d0 * as2[0] + d1 * as2[1];
        o.w = d0 * ad2[0] + d1 * ad2[1];
        node2[r] = o;
    }
}

// ---------------------------------------------------------------------------
// Layer-2 aggregation: 16 lanes per node, single float4 gather per edge
// ---------------------------------------------------------------------------
__global__ __launch_bounds__(256) void k_agg2(const int* __restrict__ rowptr,
                                              const int* __restrict__ csr,
                                              const float4* __restrict__ node2,
                                              const float* __restrict__ b2,
                                              float* __restrict__ out, int N) {
    int gid = blockIdx.x * blockDim.x + threadIdx.x;
    int n = gid >> 4;
    int ln = gid & 15;
    if (n >= N) return;
    int start = rowptr[n];
    int dcnt  = rowptr[n + 1] - start;
    float sdv = node2[n].w;
    float m = -3e38f, l = 0.f, a0 = 0.f, a1 = 0.f;
    for (int j = ln; j < dcnt; j += 16) {
        int s = csr[start + j];
        float4 hv = node2[s];
        float e = hv.z + sdv;
        e = e > 0.f ? e : NEG_SLOPE * e;
        float nm = fmaxf(m, e);
        float sc = __expf(m - nm);
        float p  = __expf(e - nm);
        a0 = a0 * sc + p * hv.x;
        a1 = a1 * sc + p * hv.y;
        l  = l * sc + p;
        m  = nm;
    }
    #pragma unroll
    for (int off = 8; off; off >>= 1) {
        float mo  = __shfl_xor(m, off, 64);
        float lo  = __shfl_xor(l, off, 64);
        float a0o = __shfl_xor(a0, off, 64);
        float a1o = __shfl_xor(a1, off, 64);
        float nm = fmaxf(m, mo);
        float sc = __expf(m - nm), so = __expf(mo - nm);
        l  = l * sc + lo * so;
        a0 = a0 * sc + a0o * so;
        a1 = a1 * sc + a1o * so;
        m  = nm;
    }
    if (ln == 0) {
        float inv = 1.f / (l + 1e-16f);
        float2 o;
        o.x = fmaf(a0, inv, b2[0]);
        o.y = fmaf(a1, inv, b2[1]);
        ((float2*)out)[n] = o;
    }
}

// ---------------------------------------------------------------------------
extern "C" void kernel_launch(void* const* d_in, const int* in_sizes, int n_in,
                              void* d_out, int out_size, void* d_ws, size_t ws_size,
                              hipStream_t stream) {
    const int N = in_sizes[0] / FH;       // 50000
    const int E = in_sizes[1] / 2;        // 800000
    const int Etot = E + N;
    const int nblk = (N + 1023) >> 10;

    const float* x     = (const float*)d_in[0];
    const int*   ei    = (const int*)d_in[1];
    const float* W1    = (const float*)d_in[2];
    const float* asrc1 = (const float*)d_in[3];
    const float* adst1 = (const float*)d_in[4];
    const float* b1    = (const float*)d_in[5];
    const float* gamma = (const float*)d_in[6];
    const float* beta  = (const float*)d_in[7];
    const float* W2    = (const float*)d_in[8];
    const float* as2   = (const float*)d_in[9];
    const float* ad2   = (const float*)d_in[10];
    const float* b2    = (const float*)d_in[11];
    float* out = (float*)d_out;

    char* ws = (char*)d_ws;
    size_t off = 0;
    auto nxt = [&](size_t bytes) {
        size_t o = off;
        off += (bytes + 255) & ~(size_t)255;
        return o;
    };
    float* h1      = (float*)(ws + nxt((size_t)N * FH * 4));
    float* hb      = (float*)(ws + nxt((size_t)N * FH * 4));
    float* ssrc1   = (float*)(ws + nxt((size_t)N * 4 * 4));
    float* sdst1   = (float*)(ws + nxt((size_t)N * 4 * 4));
    float* node2   = (float*)(ws + nxt((size_t)N * 4 * 4));
    // zero-init region: deg + bnsum + bnsq contiguous
    size_t zoff0   = off;
    int*   deg     = (int*)(ws + nxt((size_t)N * 4));
    float* bnsum   = (float*)(ws + nxt(128 * 4));
    float* bnsq    = (float*)(ws + nxt(128 * 4));
    size_t zbytes  = off - zoff0;
    int*   rowptr  = (int*)(ws + nxt((size_t)(N + 1) * 4));
    int*   csr     = (int*)(ws + nxt((size_t)Etot * 4));
    int*   blksum  = (int*)(ws + nxt((size_t)nblk * 4));
    int*   blkoff  = (int*)(ws + nxt((size_t)(nblk + 1) * 4));

    hipMemsetAsync(ws + zoff0, 0, zbytes, stream);

    dim3 g1((N + 63) / 64, 2);
    k_gemm1<<<g1, 256, 0, stream>>>(x, W1, asrc1, adst1, h1, ssrc1, sdst1, N);
    k_count<<<(Etot + 255) / 256, 256, 0, stream>>>(ei, E, N, deg);
    k_scan1<<<nblk, 1024, 0, stream>>>(deg, rowptr, blksum, N);
    k_scan2<<<1, 1024, 0, stream>>>(blksum, blkoff, nblk);
    k_scan3<<<(N + 256) / 256, 256, 0, stream>>>(rowptr, blkoff, N);
    k_fill<<<(Etot + 255) / 256, 256, 0, stream>>>(ei, E, N, rowptr, deg, csr);
    k_agg1<<<(N + 3) / 4, 256, 0, stream>>>(rowptr, csr, h1, ssrc1, sdst1, b1, hb, N);
    k_bnstat<<<512, 256, 0, stream>>>((const float4*)hb, bnsum, bnsq, N);
    k_bn2<<<(N + 7) / 8, 256, 0, stream>>>((const float4*)hb, bnsum, bnsq, gamma, beta,
                                           W2, as2, ad2, (float4*)node2, N,
                                           1.0f / (float)N);
    k_agg2<<<(N * 16 + 255) / 256, 256, 0, stream>>>(rowptr, csr, (const float4*)node2,
                                                     b2, out, N);
}

// Round 8
// 335.011 us; speedup vs baseline: 1.5516x; 1.0466x over previous
//
#include <hip/hip_runtime.h>
#include <hip/hip_bf16.h>
#include <hip/hip_fp16.h>
#include <math.h>

#define FH 128     // hidden = heads(4) * C(32)
#define NEG_SLOPE 0.2f
#define BN_EPS 1e-5f

// ---------------------------------------------------------------------------
// GEMM1: h1 = x @ W1 [N,128]x[128,128], fused per-(node,head) attention scores.
// h1 is stored ONLY as packed fp16 (sole consumer is agg1's gather).
// tile 64 rows x 64 cols, thread computes 2 rows x 8 cols. grid (ceil(N/64), 2)
// ---------------------------------------------------------------------------
__global__ __launch_bounds__(256) void k_gemm1(
    const float* __restrict__ x, const float* __restrict__ W,
    const float* __restrict__ asrc, const float* __restrict__ adst,
    __half* __restrict__ h1h, float* __restrict__ ssrc, float* __restrict__ sdst,
    int N)
{
    __shared__ float xs[64][132];    // +4 pad: bank (4r+k)%32 distinct per r
    __shared__ float Ws[128][64];
    const int t = threadIdx.x;
    const int row0 = blockIdx.x * 64;
    const int col0 = blockIdx.y * 64;

    #pragma unroll
    for (int i = 0; i < 8; ++i) {
        int f = (i * 256 + t) * 4;
        int r = f >> 7, c = f & 127;
        float4 v = make_float4(0.f, 0.f, 0.f, 0.f);
        if (row0 + r < N) v = *(const float4*)(x + (size_t)(row0 + r) * FH + c);
        xs[r][c] = v.x; xs[r][c + 1] = v.y; xs[r][c + 2] = v.z; xs[r][c + 3] = v.w;
    }
    #pragma unroll
    for (int i = 0; i < 8; ++i) {
        int f = (i * 256 + t) * 4;
        int k = f >> 6, c = f & 63;
        *(float4*)&Ws[k][c] = *(const float4*)(W + (size_t)k * FH + col0 + c);
    }
    __syncthreads();

    const int r  = t >> 3;           // 0..31 -> rows r and r+32
    const int cq = (t & 7) * 8;      // 0..56
    float accA[8] = {0,0,0,0,0,0,0,0};
    float accB[8] = {0,0,0,0,0,0,0,0};
    #pragma unroll 4
    for (int k = 0; k < 128; ++k) {
        float xa = xs[r][k];
        float xb = xs[r + 32][k];
        float4 w0 = *(const float4*)&Ws[k][cq];
        float4 w1 = *(const float4*)&Ws[k][cq + 4];
        accA[0] = fmaf(xa, w0.x, accA[0]); accA[1] = fmaf(xa, w0.y, accA[1]);
        accA[2] = fmaf(xa, w0.z, accA[2]); accA[3] = fmaf(xa, w0.w, accA[3]);
        accA[4] = fmaf(xa, w1.x, accA[4]); accA[5] = fmaf(xa, w1.y, accA[5]);
        accA[6] = fmaf(xa, w1.z, accA[6]); accA[7] = fmaf(xa, w1.w, accA[7]);
        accB[0] = fmaf(xb, w0.x, accB[0]); accB[1] = fmaf(xb, w0.y, accB[1]);
        accB[2] = fmaf(xb, w0.z, accB[2]); accB[3] = fmaf(xb, w0.w, accB[3]);
        accB[4] = fmaf(xb, w1.x, accB[4]); accB[5] = fmaf(xb, w1.y, accB[5]);
        accB[6] = fmaf(xb, w1.z, accB[6]); accB[7] = fmaf(xb, w1.w, accB[7]);
    }

    const int hg = (col0 >> 5) + (cq >> 5);    // global head 0..3
    const int cl = cq & 31;
    float4 as0 = *(const float4*)(asrc + hg * 32 + cl);
    float4 as1 = *(const float4*)(asrc + hg * 32 + cl + 4);
    float4 ad0 = *(const float4*)(adst + hg * 32 + cl);
    float4 ad1 = *(const float4*)(adst + hg * 32 + cl + 4);
    float sA = accA[0]*as0.x + accA[1]*as0.y + accA[2]*as0.z + accA[3]*as0.w
             + accA[4]*as1.x + accA[5]*as1.y + accA[6]*as1.z + accA[7]*as1.w;
    float dA = accA[0]*ad0.x + accA[1]*ad0.y + accA[2]*ad0.z + accA[3]*ad0.w
             + accA[4]*ad1.x + accA[5]*ad1.y + accA[6]*ad1.z + accA[7]*ad1.w;
    float sB = accB[0]*as0.x + accB[1]*as0.y + accB[2]*as0.z + accB[3]*as0.w
             + accB[4]*as1.x + accB[5]*as1.y + accB[6]*as1.z + accB[7]*as1.w;
    float dB = accB[0]*ad0.x + accB[1]*ad0.y + accB[2]*ad0.z + accB[3]*ad0.w
             + accB[4]*ad1.x + accB[5]*ad1.y + accB[6]*ad1.z + accB[7]*ad1.w;
    sA += __shfl_xor(sA, 1, 64); sA += __shfl_xor(sA, 2, 64);
    dA += __shfl_xor(dA, 1, 64); dA += __shfl_xor(dA, 2, 64);
    sB += __shfl_xor(sB, 1, 64); sB += __shfl_xor(sB, 2, 64);
    dB += __shfl_xor(dB, 1, 64); dB += __shfl_xor(dB, 2, 64);

    int ra = row0 + r, rb = row0 + r + 32;
    if (ra < N) {
        __half2 ph[4];
        ph[0] = __floats2half2_rn(accA[0], accA[1]);
        ph[1] = __floats2half2_rn(accA[2], accA[3]);
        ph[2] = __floats2half2_rn(accA[4], accA[5]);
        ph[3] = __floats2half2_rn(accA[6], accA[7]);
        *(uint4*)(h1h + (size_t)ra * FH + col0 + cq) = *(uint4*)ph;
        if ((t & 3) == 0) { ssrc[ra * 4 + hg] = sA; sdst[ra * 4 + hg] = dA; }
    }
    if (rb < N) {
        __half2 ph[4];
        ph[0] = __floats2half2_rn(accB[0], accB[1]);
        ph[1] = __floats2half2_rn(accB[2], accB[3]);
        ph[2] = __floats2half2_rn(accB[4], accB[5]);
        ph[3] = __floats2half2_rn(accB[6], accB[7]);
        *(uint4*)(h1h + (size_t)rb * FH + col0 + cq) = *(uint4*)ph;
        if ((t & 3) == 0) { ssrc[rb * 4 + hg] = sB; sdst[rb * 4 + hg] = dB; }
    }
}

// ---------------------------------------------------------------------------
// CSR build
// ---------------------------------------------------------------------------
__global__ void k_count(const int* __restrict__ ei, int E, int N, int* __restrict__ deg) {
    int i = blockIdx.x * blockDim.x + threadIdx.x;
    if (i >= E + N) return;
    int d = (i < E) ? ei[E + i] : (i - E);
    atomicAdd(&deg[d], 1);
}

// hierarchical scan, stage 1
__global__ __launch_bounds__(1024) void k_scan1(const int* __restrict__ deg,
                                                int* __restrict__ rowptr,
                                                int* __restrict__ blksum, int N) {
    int t = threadIdx.x;
    int i = blockIdx.x * 1024 + t;
    int v = (i < N) ? deg[i] : 0;
    int lane = t & 63, w = t >> 6;
    int incl = v;
    #pragma unroll
    for (int off = 1; off < 64; off <<= 1) {
        int tmp = __shfl_up(incl, off, 64);
        if (lane >= off) incl += tmp;
    }
    __shared__ int wsum[16];
    if (lane == 63) wsum[w] = incl;
    __syncthreads();
    if (t == 0) {
        int s = 0;
        for (int k = 0; k < 16; ++k) { int x = wsum[k]; wsum[k] = s; s += x; }
    }
    __syncthreads();
    int excl = incl - v + wsum[w];
    if (i < N) rowptr[i] = excl;
    if (t == 1023) blksum[blockIdx.x] = excl + v;
}

// stage 2: single block scans the (<=1024) block totals
__global__ __launch_bounds__(1024) void k_scan2(const int* __restrict__ blksum,
                                                int* __restrict__ blkoff, int nblk) {
    int t = threadIdx.x;
    int v = (t < nblk) ? blksum[t] : 0;
    int lane = t & 63, w = t >> 6;
    int incl = v;
    #pragma unroll
    for (int off = 1; off < 64; off <<= 1) {
        int tmp = __shfl_up(incl, off, 64);
        if (lane >= off) incl += tmp;
    }
    __shared__ int wsum[16];
    if (lane == 63) wsum[w] = incl;
    __syncthreads();
    if (t == 0) {
        int s = 0;
        for (int k = 0; k < 16; ++k) { int x = wsum[k]; wsum[k] = s; s += x; }
    }
    __syncthreads();
    int excl = incl - v + wsum[w];
    if (t < nblk) blkoff[t] = excl;
    if (t == nblk - 1) blkoff[nblk] = excl + v;
}

// stage 3: add block offsets; rowptr[N] = total
__global__ void k_scan3(int* __restrict__ rowptr, const int* __restrict__ blkoff, int N) {
    int i = blockIdx.x * blockDim.x + threadIdx.x;
    if (i > N) return;
    if (i == N) rowptr[N] = blkoff[(N + 1023) >> 10];
    else        rowptr[i] += blkoff[i >> 10];
}

// fill: slot index via atomicSub on deg (deg dead after scan)
__global__ void k_fill(const int* __restrict__ ei, int E, int N,
                       const int* __restrict__ rowptr, int* __restrict__ deg,
                       int* __restrict__ csr) {
    int i = blockIdx.x * blockDim.x + threadIdx.x;
    if (i >= E + N) return;
    int s, d;
    if (i < E) { s = ei[i]; d = ei[E + i]; }
    else       { s = i - E; d = i - E; }
    int pos = atomicSub(&deg[d], 1) - 1;
    csr[rowptr[d] + pos] = s;
}

// ---------------------------------------------------------------------------
// Layer-1 aggregation, one wave per dst node.
// pass 1: MAX-only over edges (lanes split, butterfly) — no exp, no rescale.
// pass 2: p = exp(e-M); l += p; acc += p * h1_fp16[src]  (dependency-free);
//         divide by l at the end (denom identical across lanes of a head).
// ---------------------------------------------------------------------------
__global__ __launch_bounds__(256) void k_agg1(
    const int* __restrict__ rowptr, const int* __restrict__ csr,
    const __half* __restrict__ h1h, const float* __restrict__ ssrc,
    const float* __restrict__ sdst, const float* __restrict__ b1,
    float* __restrict__ out, int N)
{
    int n = (blockIdx.x * blockDim.x + threadIdx.x) >> 6;
    int lane = threadIdx.x & 63;
    if (n >= N) return;
    int start = rowptr[n];
    int dcnt  = rowptr[n + 1] - start;

    float4 sd4 = *(const float4*)(sdst + n * 4);
    float mx = -3e38f, my = -3e38f, mz = -3e38f, mw = -3e38f;
    for (int j = lane; j < dcnt; j += 64) {
        int s = csr[start + j];
        float4 sv = *(const float4*)(ssrc + s * 4);
        float ex = sv.x + sd4.x; ex = fmaxf(ex, NEG_SLOPE * ex);
        float ey = sv.y + sd4.y; ey = fmaxf(ey, NEG_SLOPE * ey);
        float ez = sv.z + sd4.z; ez = fmaxf(ez, NEG_SLOPE * ez);
        float ew = sv.w + sd4.w; ew = fmaxf(ew, NEG_SLOPE * ew);
        mx = fmaxf(mx, ex); my = fmaxf(my, ey);
        mz = fmaxf(mz, ez); mw = fmaxf(mw, ew);
    }
    #pragma unroll
    for (int off = 32; off; off >>= 1) {
        mx = fmaxf(mx, __shfl_xor(mx, off, 64));
        my = fmaxf(my, __shfl_xor(my, off, 64));
        mz = fmaxf(mz, __shfl_xor(mz, off, 64));
        mw = fmaxf(mw, __shfl_xor(mw, off, 64));
    }

    int h = lane >> 4;                 // head of channels {2*lane, 2*lane+1}
    float Mh  = h == 0 ? mx : h == 1 ? my : h == 2 ? mz : mw;
    float sdh = h == 0 ? sd4.x : h == 1 ? sd4.y : h == 2 ? sd4.z : sd4.w;

    float ax = 0.f, ay = 0.f, l = 0.f;
    const __half2* h1v = (const __half2*)h1h;
    #pragma unroll 4
    for (int j = 0; j < dcnt; ++j) {
        int s = csr[start + j];
        float e = ssrc[s * 4 + h] + sdh;
        e = fmaxf(e, NEG_SLOPE * e);
        float p = __expf(e - Mh);
        l += p;
        float2 v = __half22float2(h1v[((size_t)s << 6) + lane]);
        ax = fmaf(p, v.x, ax);
        ay = fmaf(p, v.y, ay);
    }
    float inv = 1.f / (l + 1e-16f);
    float2 b1v = ((const float2*)b1)[lane];
    float2 o;
    o.x = fmaf(ax, inv, b1v.x);
    o.y = fmaf(ay, inv, b1v.y);
    ((float2*)out)[((size_t)n << 6) + lane] = o;
}

// ---------------------------------------------------------------------------
// BN column stats: 512 blocks x 256 thr, float4, LDS tree + 1 atomic round
// ---------------------------------------------------------------------------
__global__ __launch_bounds__(256) void k_bnstat(const float4* __restrict__ hb4,
                                                float* __restrict__ bnsum,
                                                float* __restrict__ bnsq, int N) {
    __shared__ float rs[8][128];
    __shared__ float rq[8][128];
    int t = threadIdx.x;
    int rg = t >> 5, c4 = t & 31;
    float sx = 0, sy = 0, sz = 0, sw = 0, qx = 0, qy = 0, qz = 0, qw = 0;
    for (int r = blockIdx.x * 8 + rg; r < N; r += gridDim.x * 8) {
        float4 v = hb4[(size_t)r * 32 + c4];
        sx += v.x; sy += v.y; sz += v.z; sw += v.w;
        qx = fmaf(v.x, v.x, qx); qy = fmaf(v.y, v.y, qy);
        qz = fmaf(v.z, v.z, qz); qw = fmaf(v.w, v.w, qw);
    }
    int c = c4 * 4;
    rs[rg][c] = sx; rs[rg][c+1] = sy; rs[rg][c+2] = sz; rs[rg][c+3] = sw;
    rq[rg][c] = qx; rq[rg][c+1] = qy; rq[rg][c+2] = qz; rq[rg][c+3] = qw;
    __syncthreads();
    for (int k = 4; k; k >>= 1) {
        if (rg < k) {
            rs[rg][c]   += rs[rg+k][c];   rs[rg][c+1] += rs[rg+k][c+1];
            rs[rg][c+2] += rs[rg+k][c+2]; rs[rg][c+3] += rs[rg+k][c+3];
            rq[rg][c]   += rq[rg+k][c];   rq[rg][c+1] += rq[rg+k][c+1];
            rq[rg][c+2] += rq[rg+k][c+2]; rq[rg][c+3] += rq[rg+k][c+3];
        }
        __syncthreads();
    }
    if (t < 32) {
        int cc = t * 4;
        atomicAdd(&bnsum[cc],   rs[0][cc]);   atomicAdd(&bnsum[cc+1], rs[0][cc+1]);
        atomicAdd(&bnsum[cc+2], rs[0][cc+2]); atomicAdd(&bnsum[cc+3], rs[0][cc+3]);
        atomicAdd(&bnsq[cc],    rq[0][cc]);   atomicAdd(&bnsq[cc+1],  rq[0][cc+1]);
        atomicAdd(&bnsq[cc+2],  rq[0][cc+2]); atomicAdd(&bnsq[cc+3],  rq[0][cc+3]);
    }
}

// ---------------------------------------------------------------------------
// Fused BN-apply + ELU + layer-2 linear + scores. Packs (h2x,h2y,ss2,sd2).
// ---------------------------------------------------------------------------
__global__ __launch_bounds__(256) void k_bn2(const float4* __restrict__ hb4,
                                             const float* __restrict__ bnsum,
                                             const float* __restrict__ bnsq,
                                             const float* __restrict__ gamma,
                                             const float* __restrict__ beta,
                                             const float* __restrict__ W2,
                                             const float* __restrict__ as2,
                                             const float* __restrict__ ad2,
                                             float4* __restrict__ node2,
                                             int N, float invN) {
    int t = threadIdx.x;
    int rl = t >> 5, c4 = t & 31;
    int r = blockIdx.x * 8 + rl;
    if (r >= N) return;
    int c = c4 * 4;
    float4 s4 = *(const float4*)(bnsum + c);
    float4 q4 = *(const float4*)(bnsq + c);
    float4 g4 = *(const float4*)(gamma + c);
    float4 be4 = *(const float4*)(beta + c);
    float mu0 = s4.x * invN, mu1 = s4.y * invN, mu2 = s4.z * invN, mu3 = s4.w * invN;
    float sc0 = rsqrtf(q4.x * invN - mu0 * mu0 + BN_EPS) * g4.x;
    float sc1 = rsqrtf(q4.y * invN - mu1 * mu1 + BN_EPS) * g4.y;
    float sc2 = rsqrtf(q4.z * invN - mu2 * mu2 + BN_EPS) * g4.z;
    float sc3 = rsqrtf(q4.w * invN - mu3 * mu3 + BN_EPS) * g4.w;
    float sh0 = be4.x - mu0 * sc0, sh1 = be4.y - mu1 * sc1;
    float sh2 = be4.z - mu2 * sc2, sh3 = be4.w - mu3 * sc3;

    float4 v = hb4[(size_t)r * 32 + c4];
    float t0 = fmaf(v.x, sc0, sh0);
    float t1 = fmaf(v.y, sc1, sh1);
    float t2 = fmaf(v.z, sc2, sh2);
    float t3 = fmaf(v.w, sc3, sh3);
    t0 = t0 > 0.f ? t0 : expm1f(t0);
    t1 = t1 > 0.f ? t1 : expm1f(t1);
    t2 = t2 > 0.f ? t2 : expm1f(t2);
    t3 = t3 > 0.f ? t3 : expm1f(t3);
    float d0 = t0 * W2[c * 2]       + t1 * W2[(c + 1) * 2]
             + t2 * W2[(c + 2) * 2] + t3 * W2[(c + 3) * 2];
    float d1 = t0 * W2[c * 2 + 1]       + t1 * W2[(c + 1) * 2 + 1]
             + t2 * W2[(c + 2) * 2 + 1] + t3 * W2[(c + 3) * 2 + 1];
    #pragma unroll
    for (int off = 16; off; off >>= 1) {
        d0 += __shfl_xor(d0, off, 64);
        d1 += __shfl_xor(d1, off, 64);
    }
    if (c4 == 0) {
        float4 o;
        o.x = d0; o.y = d1;
        o.z = d0 * as2[0] + d1 * as2[1];
        o.w = d0 * ad2[0] + d1 * ad2[1];
        node2[r] = o;
    }
}

// ---------------------------------------------------------------------------
// Layer-2 aggregation: 16 lanes per node, single float4 gather per edge
// ---------------------------------------------------------------------------
__global__ __launch_bounds__(256) void k_agg2(const int* __restrict__ rowptr,
                                              const int* __restrict__ csr,
                                              const float4* __restrict__ node2,
                                              const float* __restrict__ b2,
                                              float* __restrict__ out, int N) {
    int gid = blockIdx.x * blockDim.x + threadIdx.x;
    int n = gid >> 4;
    int ln = gid & 15;
    if (n >= N) return;
    int start = rowptr[n];
    int dcnt  = rowptr[n + 1] - start;
    float sdv = node2[n].w;
    float m = -3e38f, l = 0.f, a0 = 0.f, a1 = 0.f;
    for (int j = ln; j < dcnt; j += 16) {
        int s = csr[start + j];
        float4 hv = node2[s];
        float e = hv.z + sdv;
        e = fmaxf(e, NEG_SLOPE * e);
        float nm = fmaxf(m, e);
        float sc = __expf(m - nm);
        float p  = __expf(e - nm);
        a0 = a0 * sc + p * hv.x;
        a1 = a1 * sc + p * hv.y;
        l  = l * sc + p;
        m  = nm;
    }
    #pragma unroll
    for (int off = 8; off; off >>= 1) {
        float mo  = __shfl_xor(m, off, 64);
        float lo  = __shfl_xor(l, off, 64);
        float a0o = __shfl_xor(a0, off, 64);
        float a1o = __shfl_xor(a1, off, 64);
        float nm = fmaxf(m, mo);
        float sc = __expf(m - nm), so = __expf(mo - nm);
        l  = l * sc + lo * so;
        a0 = a0 * sc + a0o * so;
        a1 = a1 * sc + a1o * so;
        m  = nm;
    }
    if (ln == 0) {
        float inv = 1.f / (l + 1e-16f);
        float2 o;
        o.x = fmaf(a0, inv, b2[0]);
        o.y = fmaf(a1, inv, b2[1]);
        ((float2*)out)[n] = o;
    }
}

// ---------------------------------------------------------------------------
extern "C" void kernel_launch(void* const* d_in, const int* in_sizes, int n_in,
                              void* d_out, int out_size, void* d_ws, size_t ws_size,
                              hipStream_t stream) {
    const int N = in_sizes[0] / FH;       // 50000
    const int E = in_sizes[1] / 2;        // 800000
    const int Etot = E + N;
    const int nblk = (N + 1023) >> 10;

    const float* x     = (const float*)d_in[0];
    const int*   ei    = (const int*)d_in[1];
    const float* W1    = (const float*)d_in[2];
    const float* asrc1 = (const float*)d_in[3];
    const float* adst1 = (const float*)d_in[4];
    const float* b1    = (const float*)d_in[5];
    const float* gamma = (const float*)d_in[6];
    const float* beta  = (const float*)d_in[7];
    const float* W2    = (const float*)d_in[8];
    const float* as2   = (const float*)d_in[9];
    const float* ad2   = (const float*)d_in[10];
    const float* b2    = (const float*)d_in[11];
    float* out = (float*)d_out;

    char* ws = (char*)d_ws;
    size_t off = 0;
    auto nxt = [&](size_t bytes) {
        size_t o = off;
        off += (bytes + 255) & ~(size_t)255;
        return o;
    };
    __half* h1h    = (__half*)(ws + nxt((size_t)N * FH * 2));
    float* hb      = (float*)(ws + nxt((size_t)N * FH * 4));
    float* ssrc1   = (float*)(ws + nxt((size_t)N * 4 * 4));
    float* sdst1   = (float*)(ws + nxt((size_t)N * 4 * 4));
    float* node2   = (float*)(ws + nxt((size_t)N * 4 * 4));
    // zero-init region: deg + bnsum + bnsq contiguous
    size_t zoff0   = off;
    int*   deg     = (int*)(ws + nxt((size_t)N * 4));
    float* bnsum   = (float*)(ws + nxt(128 * 4));
    float* bnsq    = (float*)(ws + nxt(128 * 4));
    size_t zbytes  = off - zoff0;
    int*   rowptr  = (int*)(ws + nxt((size_t)(N + 1) * 4));
    int*   csr     = (int*)(ws + nxt((size_t)Etot * 4));
    int*   blksum  = (int*)(ws + nxt((size_t)nblk * 4));
    int*   blkoff  = (int*)(ws + nxt((size_t)(nblk + 1) * 4));

    hipMemsetAsync(ws + zoff0, 0, zbytes, stream);

    dim3 g1((N + 63) / 64, 2);
    k_gemm1<<<g1, 256, 0, stream>>>(x, W1, asrc1, adst1, h1h, ssrc1, sdst1, N);
    k_count<<<(Etot + 255) / 256, 256, 0, stream>>>(ei, E, N, deg);
    k_scan1<<<nblk, 1024, 0, stream>>>(deg, rowptr, blksum, N);
    k_scan2<<<1, 1024, 0, stream>>>(blksum, blkoff, nblk);
    k_scan3<<<(N + 256) / 256, 256, 0, stream>>>(rowptr, blkoff, N);
    k_fill<<<(Etot + 255) / 256, 256, 0, stream>>>(ei, E, N, rowptr, deg, csr);
    k_agg1<<<(N + 3) / 4, 256, 0, stream>>>(rowptr, csr, h1h, ssrc1, sdst1, b1, hb, N);
    k_bnstat<<<512, 256, 0, stream>>>((const float4*)hb, bnsum, bnsq, N);
    k_bn2<<<(N + 7) / 8, 256, 0, stream>>>((const float4*)hb, bnsum, bnsq, gamma, beta,
                                           W2, as2, ad2, (float4*)node2, N,
                                           1.0f / (float)N);
    k_agg2<<<(N * 16 + 255) / 256, 256, 0, stream>>>(rowptr, csr, (const float4*)node2,
                                                     b2, out, N);
}

// Round 9
// 321.182 us; speedup vs baseline: 1.6184x; 1.0431x over previous
//
#include <hip/hip_runtime.h>
#include <hip/hip_bf16.h>
#include <hip/hip_fp16.h>
#include <math.h>

#define FH 128     // hidden = heads(4) * C(32)
#define NEG_SLOPE 0.2f
#define BN_EPS 1e-5f

// ---------------------------------------------------------------------------
// GEMM1: h1 = x @ W1 [N,128]x[128,128], fused per-(node,head) attention scores.
// h1 stored ONLY as packed fp16. Tile 256 rows x 64 cols, BK=32, 256 threads,
// 8x8 microtile, x staged TRANSPOSED so both operands are b128 LDS reads.
// grid (ceil(N/256), 2)
// ---------------------------------------------------------------------------
__global__ __launch_bounds__(256) void k_gemm1(
    const float* __restrict__ x, const float* __restrict__ W,
    const float* __restrict__ asrc, const float* __restrict__ adst,
    __half* __restrict__ h1h, float* __restrict__ ssrc, float* __restrict__ sdst,
    int N)
{
    __shared__ float xsT[32][260];   // [k][row] pad->260: reads 2-way (free), 16B aligned
    __shared__ float Ws[32][68];     // [k][col] pad->68: reads 2-way (free)
    const int t = threadIdx.x;
    const int row0 = blockIdx.x * 256;
    const int col0 = blockIdx.y * 64;
    const int tc = t & 7, rg = t >> 3;
    const int c0 = tc * 8, r0 = rg * 8;

    float acc[8][8];
    #pragma unroll
    for (int i = 0; i < 8; ++i)
        #pragma unroll
        for (int j = 0; j < 8; ++j) acc[i][j] = 0.f;

    for (int kc = 0; kc < 128; kc += 32) {
        // stage x chunk transposed: 256 rows x 32 k
        #pragma unroll
        for (int i = 0; i < 8; ++i) {
            int f4 = i * 256 + t;
            int r = f4 >> 3, kq = (f4 & 7) * 4;
            float4 v = make_float4(0.f, 0.f, 0.f, 0.f);
            if (row0 + r < N) v = *(const float4*)(x + (size_t)(row0 + r) * FH + kc + kq);
            xsT[kq][r] = v.x; xsT[kq + 1][r] = v.y;
            xsT[kq + 2][r] = v.z; xsT[kq + 3][r] = v.w;
        }
        // stage W chunk: 32 k x 64 cols
        #pragma unroll
        for (int i = 0; i < 2; ++i) {
            int f4 = i * 256 + t;
            int k = f4 >> 4, cq = (f4 & 15) * 4;
            *(float4*)&Ws[k][cq] = *(const float4*)(W + (size_t)(kc + k) * FH + col0 + cq);
        }
        __syncthreads();
        #pragma unroll 4
        for (int k = 0; k < 32; ++k) {
            float4 xa0 = *(const float4*)&xsT[k][r0];
            float4 xa1 = *(const float4*)&xsT[k][r0 + 4];
            float4 wv0 = *(const float4*)&Ws[k][c0];
            float4 wv1 = *(const float4*)&Ws[k][c0 + 4];
            float xr[8] = {xa0.x, xa0.y, xa0.z, xa0.w, xa1.x, xa1.y, xa1.z, xa1.w};
            float wc[8] = {wv0.x, wv0.y, wv0.z, wv0.w, wv1.x, wv1.y, wv1.z, wv1.w};
            #pragma unroll
            for (int i = 0; i < 8; ++i)
                #pragma unroll
                for (int j = 0; j < 8; ++j)
                    acc[i][j] = fmaf(xr[i], wc[j], acc[i][j]);
        }
        __syncthreads();
    }

    // fused scores: this thread's 8 cols lie in one head
    const int hg = (col0 + c0) >> 5;
    const int cl = (col0 + c0) & 31;
    float4 as0 = *(const float4*)(asrc + hg * 32 + cl);
    float4 as1 = *(const float4*)(asrc + hg * 32 + cl + 4);
    float4 ad0 = *(const float4*)(adst + hg * 32 + cl);
    float4 ad1 = *(const float4*)(adst + hg * 32 + cl + 4);
    float as[8] = {as0.x, as0.y, as0.z, as0.w, as1.x, as1.y, as1.z, as1.w};
    float ad[8] = {ad0.x, ad0.y, ad0.z, ad0.w, ad1.x, ad1.y, ad1.z, ad1.w};
    float sA[8], dA[8];
    #pragma unroll
    for (int i = 0; i < 8; ++i) {
        float s = 0.f, d = 0.f;
        #pragma unroll
        for (int j = 0; j < 8; ++j) {
            s = fmaf(acc[i][j], as[j], s);
            d = fmaf(acc[i][j], ad[j], d);
        }
        sA[i] = s; dA[i] = d;
    }
    // reduce across the 4 lanes (tc mod 4) sharing (rows, head)
    #pragma unroll
    for (int i = 0; i < 8; ++i) {
        sA[i] += __shfl_xor(sA[i], 1, 64); sA[i] += __shfl_xor(sA[i], 2, 64);
        dA[i] += __shfl_xor(dA[i], 1, 64); dA[i] += __shfl_xor(dA[i], 2, 64);
    }
    if ((tc & 3) == 0) {
        #pragma unroll
        for (int i = 0; i < 8; ++i) {
            int row = row0 + r0 + i;
            if (row < N) { ssrc[row * 4 + hg] = sA[i]; sdst[row * 4 + hg] = dA[i]; }
        }
    }
    // write h1 as fp16
    #pragma unroll
    for (int i = 0; i < 8; ++i) {
        int row = row0 + r0 + i;
        if (row < N) {
            __half2 ph[4];
            ph[0] = __floats2half2_rn(acc[i][0], acc[i][1]);
            ph[1] = __floats2half2_rn(acc[i][2], acc[i][3]);
            ph[2] = __floats2half2_rn(acc[i][4], acc[i][5]);
            ph[3] = __floats2half2_rn(acc[i][6], acc[i][7]);
            *(uint4*)(h1h + (size_t)row * FH + col0 + c0) = *(uint4*)ph;
        }
    }
}

// ---------------------------------------------------------------------------
// CSR build
// ---------------------------------------------------------------------------
__global__ void k_count(const int* __restrict__ ei, int E, int N, int* __restrict__ deg) {
    int i = blockIdx.x * blockDim.x + threadIdx.x;
    if (i >= E + N) return;
    int d = (i < E) ? ei[E + i] : (i - E);
    atomicAdd(&deg[d], 1);
}

// hierarchical scan, stage 1
__global__ __launch_bounds__(1024) void k_scan1(const int* __restrict__ deg,
                                                int* __restrict__ rowptr,
                                                int* __restrict__ blksum, int N) {
    int t = threadIdx.x;
    int i = blockIdx.x * 1024 + t;
    int v = (i < N) ? deg[i] : 0;
    int lane = t & 63, w = t >> 6;
    int incl = v;
    #pragma unroll
    for (int off = 1; off < 64; off <<= 1) {
        int tmp = __shfl_up(incl, off, 64);
        if (lane >= off) incl += tmp;
    }
    __shared__ int wsum[16];
    if (lane == 63) wsum[w] = incl;
    __syncthreads();
    if (t == 0) {
        int s = 0;
        for (int k = 0; k < 16; ++k) { int x = wsum[k]; wsum[k] = s; s += x; }
    }
    __syncthreads();
    int excl = incl - v + wsum[w];
    if (i < N) rowptr[i] = excl;
    if (t == 1023) blksum[blockIdx.x] = excl + v;
}

// stage 2: single block scans the (<=1024) block totals
__global__ __launch_bounds__(1024) void k_scan2(const int* __restrict__ blksum,
                                                int* __restrict__ blkoff, int nblk) {
    int t = threadIdx.x;
    int v = (t < nblk) ? blksum[t] : 0;
    int lane = t & 63, w = t >> 6;
    int incl = v;
    #pragma unroll
    for (int off = 1; off < 64; off <<= 1) {
        int tmp = __shfl_up(incl, off, 64);
        if (lane >= off) incl += tmp;
    }
    __shared__ int wsum[16];
    if (lane == 63) wsum[w] = incl;
    __syncthreads();
    if (t == 0) {
        int s = 0;
        for (int k = 0; k < 16; ++k) { int x = wsum[k]; wsum[k] = s; s += x; }
    }
    __syncthreads();
    int excl = incl - v + wsum[w];
    if (t < nblk) blkoff[t] = excl;
    if (t == nblk - 1) blkoff[nblk] = excl + v;
}

// stage 3: add block offsets; rowptr[N] = total
__global__ void k_scan3(int* __restrict__ rowptr, const int* __restrict__ blkoff, int N) {
    int i = blockIdx.x * blockDim.x + threadIdx.x;
    if (i > N) return;
    if (i == N) rowptr[N] = blkoff[(N + 1023) >> 10];
    else        rowptr[i] += blkoff[i >> 10];
}

// fill: place edge into CSR slot AND precompute per-edge softmax weights
// alpha[slot][h] = exp(leaky(ssrc[s][h] + sdst[d][h]))  (no max-shift: |e|<~6)
__global__ void k_fill(const int* __restrict__ ei, int E, int N,
                       const int* __restrict__ rowptr, int* __restrict__ deg,
                       const float4* __restrict__ ssrc4, const float4* __restrict__ sdst4,
                       int* __restrict__ csr, float4* __restrict__ alpha4) {
    int i = blockIdx.x * blockDim.x + threadIdx.x;
    if (i >= E + N) return;
    int s, d;
    if (i < E) { s = ei[i]; d = ei[E + i]; }
    else       { s = i - E; d = i - E; }
    int pos = atomicSub(&deg[d], 1) - 1;
    int slot = rowptr[d] + pos;
    csr[slot] = s;
    float4 sv = ssrc4[s];
    float4 dv = sdst4[d];
    float ex = sv.x + dv.x; ex = fmaxf(ex, NEG_SLOPE * ex);
    float ey = sv.y + dv.y; ey = fmaxf(ey, NEG_SLOPE * ey);
    float ez = sv.z + dv.z; ez = fmaxf(ez, NEG_SLOPE * ez);
    float ew = sv.w + dv.w; ew = fmaxf(ew, NEG_SLOPE * ew);
    float4 a;
    a.x = __expf(ex); a.y = __expf(ey); a.z = __expf(ez); a.w = __expf(ew);
    alpha4[slot] = a;
}

// ---------------------------------------------------------------------------
// Layer-1 aggregation, one wave per dst node: single dependency-free pass.
// lane owns channels {2*lane, 2*lane+1} (head h=lane>>4).
// acc += alpha[slot][h] * h1_fp16[src]; l += alpha; divide at end.
// ---------------------------------------------------------------------------
__global__ __launch_bounds__(256) void k_agg1(
    const int* __restrict__ rowptr, const int* __restrict__ csr,
    const float* __restrict__ alph, const __half* __restrict__ h1h,
    const float* __restrict__ b1, float* __restrict__ out, int N)
{
    int n = (blockIdx.x * blockDim.x + threadIdx.x) >> 6;
    int lane = threadIdx.x & 63;
    if (n >= N) return;
    int start = rowptr[n];
    int dcnt  = rowptr[n + 1] - start;
    int h = lane >> 4;

    float ax = 0.f, ay = 0.f, l = 0.f;
    const __half2* h1v = (const __half2*)h1h;
    #pragma unroll 4
    for (int j = 0; j < dcnt; ++j) {
        int idx = start + j;
        int s = csr[idx];
        float a = alph[idx * 4 + h];
        l += a;
        float2 v = __half22float2(h1v[((size_t)s << 6) + lane]);
        ax = fmaf(a, v.x, ax);
        ay = fmaf(a, v.y, ay);
    }
    float inv = 1.f / (l + 1e-16f);
    float2 b1v = ((const float2*)b1)[lane];
    float2 o;
    o.x = fmaf(ax, inv, b1v.x);
    o.y = fmaf(ay, inv, b1v.y);
    ((float2*)out)[((size_t)n << 6) + lane] = o;
}

// ---------------------------------------------------------------------------
// BN column stats: 512 blocks x 256 thr, float4, LDS tree + 1 atomic round
// ---------------------------------------------------------------------------
__global__ __launch_bounds__(256) void k_bnstat(const float4* __restrict__ hb4,
                                                float* __restrict__ bnsum,
                                                float* __restrict__ bnsq, int N) {
    __shared__ float rs[8][128];
    __shared__ float rq[8][128];
    int t = threadIdx.x;
    int rg = t >> 5, c4 = t & 31;
    float sx = 0, sy = 0, sz = 0, sw = 0, qx = 0, qy = 0, qz = 0, qw = 0;
    for (int r = blockIdx.x * 8 + rg; r < N; r += gridDim.x * 8) {
        float4 v = hb4[(size_t)r * 32 + c4];
        sx += v.x; sy += v.y; sz += v.z; sw += v.w;
        qx = fmaf(v.x, v.x, qx); qy = fmaf(v.y, v.y, qy);
        qz = fmaf(v.z, v.z, qz); qw = fmaf(v.w, v.w, qw);
    }
    int c = c4 * 4;
    rs[rg][c] = sx; rs[rg][c+1] = sy; rs[rg][c+2] = sz; rs[rg][c+3] = sw;
    rq[rg][c] = qx; rq[rg][c+1] = qy; rq[rg][c+2] = qz; rq[rg][c+3] = qw;
    __syncthreads();
    for (int k = 4; k; k >>= 1) {
        if (rg < k) {
            rs[rg][c]   += rs[rg+k][c];   rs[rg][c+1] += rs[rg+k][c+1];
            rs[rg][c+2] += rs[rg+k][c+2]; rs[rg][c+3] += rs[rg+k][c+3];
            rq[rg][c]   += rq[rg+k][c];   rq[rg][c+1] += rq[rg+k][c+1];
            rq[rg][c+2] += rq[rg+k][c+2]; rq[rg][c+3] += rq[rg+k][c+3];
        }
        __syncthreads();
    }
    if (t < 32) {
        int cc = t * 4;
        atomicAdd(&bnsum[cc],   rs[0][cc]);   atomicAdd(&bnsum[cc+1], rs[0][cc+1]);
        atomicAdd(&bnsum[cc+2], rs[0][cc+2]); atomicAdd(&bnsum[cc+3], rs[0][cc+3]);
        atomicAdd(&bnsq[cc],    rq[0][cc]);   atomicAdd(&bnsq[cc+1],  rq[0][cc+1]);
        atomicAdd(&bnsq[cc+2],  rq[0][cc+2]); atomicAdd(&bnsq[cc+3],  rq[0][cc+3]);
    }
}

// ---------------------------------------------------------------------------
// Fused BN-apply + ELU + layer-2 linear + scores. Packs (h2x,h2y,ss2,sd2).
// ---------------------------------------------------------------------------
__global__ __launch_bounds__(256) void k_bn2(const float4* __restrict__ hb4,
                                             const float* __restrict__ bnsum,
                                             const float* __restrict__ bnsq,
                                             const float* __restrict__ gamma,
                                             const float* __restrict__ beta,
                                             const float* __restrict__ W2,
                                             const float* __restrict__ as2,
                                             const float* __restrict__ ad2,
                                             float4* __restrict__ node2,
                                             int N, float invN) {
    int t = threadIdx.x;
    int rl = t >> 5, c4 = t & 31;
    int r = blockIdx.x * 8 + rl;
    if (r >= N) return;
    int c = c4 * 4;
    float4 s4 = *(const float4*)(bnsum + c);
    float4 q4 = *(const float4*)(bnsq + c);
    float4 g4 = *(const float4*)(gamma + c);
    float4 be4 = *(const float4*)(beta + c);
    float mu0 = s4.x * invN, mu1 = s4.y * invN, mu2 = s4.z * invN, mu3 = s4.w * invN;
    float sc0 = rsqrtf(q4.x * invN - mu0 * mu0 + BN_EPS) * g4.x;
    float sc1 = rsqrtf(q4.y * invN - mu1 * mu1 + BN_EPS) * g4.y;
    float sc2 = rsqrtf(q4.z * invN - mu2 * mu2 + BN_EPS) * g4.z;
    float sc3 = rsqrtf(q4.w * invN - mu3 * mu3 + BN_EPS) * g4.w;
    float sh0 = be4.x - mu0 * sc0, sh1 = be4.y - mu1 * sc1;
    float sh2 = be4.z - mu2 * sc2, sh3 = be4.w - mu3 * sc3;

    float4 v = hb4[(size_t)r * 32 + c4];
    float t0 = fmaf(v.x, sc0, sh0);
    float t1 = fmaf(v.y, sc1, sh1);
    float t2 = fmaf(v.z, sc2, sh2);
    float t3 = fmaf(v.w, sc3, sh3);
    t0 = t0 > 0.f ? t0 : expm1f(t0);
    t1 = t1 > 0.f ? t1 : expm1f(t1);
    t2 = t2 > 0.f ? t2 : expm1f(t2);
    t3 = t3 > 0.f ? t3 : expm1f(t3);
    float d0 = t0 * W2[c * 2]       + t1 * W2[(c + 1) * 2]
             + t2 * W2[(c + 2) * 2] + t3 * W2[(c + 3) * 2];
    float d1 = t0 * W2[c * 2 + 1]       + t1 * W2[(c + 1) * 2 + 1]
             + t2 * W2[(c + 2) * 2 + 1] + t3 * W2[(c + 3) * 2 + 1];
    #pragma unroll
    for (int off = 16; off; off >>= 1) {
        d0 += __shfl_xor(d0, off, 64);
        d1 += __shfl_xor(d1, off, 64);
    }
    if (c4 == 0) {
        float4 o;
        o.x = d0; o.y = d1;
        o.z = d0 * as2[0] + d1 * as2[1];
        o.w = d0 * ad2[0] + d1 * ad2[1];
        node2[r] = o;
    }
}

// ---------------------------------------------------------------------------
// Layer-2 aggregation: 16 lanes per node, single float4 gather per edge
// ---------------------------------------------------------------------------
__global__ __launch_bounds__(256) void k_agg2(const int* __restrict__ rowptr,
                                              const int* __restrict__ csr,
                                              const float4* __restrict__ node2,
                                              const float* __restrict__ b2,
                                              float* __restrict__ out, int N) {
    int gid = blockIdx.x * blockDim.x + threadIdx.x;
    int n = gid >> 4;
    int ln = gid & 15;
    if (n >= N) return;
    int start = rowptr[n];
    int dcnt  = rowptr[n + 1] - start;
    float sdv = node2[n].w;
    float m = -3e38f, l = 0.f, a0 = 0.f, a1 = 0.f;
    for (int j = ln; j < dcnt; j += 16) {
        int s = csr[start + j];
        float4 hv = node2[s];
        float e = hv.z + sdv;
        e = fmaxf(e, NEG_SLOPE * e);
        float nm = fmaxf(m, e);
        float sc = __expf(m - nm);
        float p  = __expf(e - nm);
        a0 = a0 * sc + p * hv.x;
        a1 = a1 * sc + p * hv.y;
        l  = l * sc + p;
        m  = nm;
    }
    #pragma unroll
    for (int off = 8; off; off >>= 1) {
        float mo  = __shfl_xor(m, off, 64);
        float lo  = __shfl_xor(l, off, 64);
        float a0o = __shfl_xor(a0, off, 64);
        float a1o = __shfl_xor(a1, off, 64);
        float nm = fmaxf(m, mo);
        float sc = __expf(m - nm), so = __expf(mo - nm);
        l  = l * sc + lo * so;
        a0 = a0 * sc + a0o * so;
        a1 = a1 * sc + a1o * so;
        m  = nm;
    }
    if (ln == 0) {
        float inv = 1.f / (l + 1e-16f);
        float2 o;
        o.x = fmaf(a0, inv, b2[0]);
        o.y = fmaf(a1, inv, b2[1]);
        ((float2*)out)[n] = o;
    }
}

// ---------------------------------------------------------------------------
extern "C" void kernel_launch(void* const* d_in, const int* in_sizes, int n_in,
                              void* d_out, int out_size, void* d_ws, size_t ws_size,
                              hipStream_t stream) {
    const int N = in_sizes[0] / FH;       // 50000
    const int E = in_sizes[1] / 2;        // 800000
    const int Etot = E + N;
    const int nblk = (N + 1023) >> 10;

    const float* x     = (const float*)d_in[0];
    const int*   ei    = (const int*)d_in[1];
    const float* W1    = (const float*)d_in[2];
    const float* asrc1 = (const float*)d_in[3];
    const float* adst1 = (const float*)d_in[4];
    const float* b1    = (const float*)d_in[5];
    const float* gamma = (const float*)d_in[6];
    const float* beta  = (const float*)d_in[7];
    const float* W2    = (const float*)d_in[8];
    const float* as2   = (const float*)d_in[9];
    const float* ad2   = (const float*)d_in[10];
    const float* b2    = (const float*)d_in[11];
    float* out = (float*)d_out;

    char* ws = (char*)d_ws;
    size_t off = 0;
    auto nxt = [&](size_t bytes) {
        size_t o = off;
        off += (bytes + 255) & ~(size_t)255;
        return o;
    };
    __half* h1h    = (__half*)(ws + nxt((size_t)N * FH * 2));
    float* hb      = (float*)(ws + nxt((size_t)N * FH * 4));
    float* ssrc1   = (float*)(ws + nxt((size_t)N * 4 * 4));
    float* sdst1   = (float*)(ws + nxt((size_t)N * 4 * 4));
    float* node2   = (float*)(ws + nxt((size_t)N * 4 * 4));
    float* alpha   = (float*)(ws + nxt((size_t)Etot * 4 * 4));
    // zero-init region: deg + bnsum + bnsq contiguous
    size_t zoff0   = off;
    int*   deg     = (int*)(ws + nxt((size_t)N * 4));
    float* bnsum   = (float*)(ws + nxt(128 * 4));
    float* bnsq    = (float*)(ws + nxt(128 * 4));
    size_t zbytes  = off - zoff0;
    int*   rowptr  = (int*)(ws + nxt((size_t)(N + 1) * 4));
    int*   csr     = (int*)(ws + nxt((size_t)Etot * 4));
    int*   blksum  = (int*)(ws + nxt((size_t)nblk * 4));
    int*   blkoff  = (int*)(ws + nxt((size_t)(nblk + 1) * 4));

    hipMemsetAsync(ws + zoff0, 0, zbytes, stream);

    dim3 g1((N + 255) / 256, 2);
    k_gemm1<<<g1, 256, 0, stream>>>(x, W1, asrc1, adst1, h1h, ssrc1, sdst1, N);
    k_count<<<(Etot + 255) / 256, 256, 0, stream>>>(ei, E, N, deg);
    k_scan1<<<nblk, 1024, 0, stream>>>(deg, rowptr, blksum, N);
    k_scan2<<<1, 1024, 0, stream>>>(blksum, blkoff, nblk);
    k_scan3<<<(N + 256) / 256, 256, 0, stream>>>(rowptr, blkoff, N);
    k_fill<<<(Etot + 255) / 256, 256, 0, stream>>>(ei, E, N, rowptr, deg,
                                                   (const float4*)ssrc1,
                                                   (const float4*)sdst1,
                                                   csr, (float4*)alpha);
    k_agg1<<<(N + 3) / 4, 256, 0, stream>>>(rowptr, csr, alpha, h1h, b1, hb, N);
    k_bnstat<<<512, 256, 0, stream>>>((const float4*)hb, bnsum, bnsq, N);
    k_bn2<<<(N + 7) / 8, 256, 0, stream>>>((const float4*)hb, bnsum, bnsq, gamma, beta,
                                           W2, as2, ad2, (float4*)node2, N,
                                           1.0f / (float)N);
    k_agg2<<<(N * 16 + 255) / 256, 256, 0, stream>>>(rowptr, csr, (const float4*)node2,
                                                     b2, out, N);
}

// Round 10
// 293.193 us; speedup vs baseline: 1.7729x; 1.0955x over previous
//
#include <hip/hip_runtime.h>
#include <hip/hip_bf16.h>
#include <hip/hip_fp16.h>
#include <math.h>

#define FH 128     // hidden = heads(4) * C(32)
#define NEG_SLOPE 0.2f
#define BN_EPS 1e-5f
#define NBLK_BN 512

// ---------------------------------------------------------------------------
// GEMM1: h1 = x @ W1 [N,128]x[128,128], fused per-(node,head) attention scores.
// h1 stored ONLY as packed fp16. Tile 256 rows x 64 cols, BK=32, 256 threads,
// 8x8 microtile, x staged TRANSPOSED so both operands are b128 LDS reads.
// grid (ceil(N/256), 2)
// ---------------------------------------------------------------------------
__global__ __launch_bounds__(256) void k_gemm1(
    const float* __restrict__ x, const float* __restrict__ W,
    const float* __restrict__ asrc, const float* __restrict__ adst,
    __half* __restrict__ h1h, float* __restrict__ ssrc, float* __restrict__ sdst,
    int N)
{
    __shared__ float xsT[32][260];   // [k][row] pad->260
    __shared__ float Ws[32][68];     // [k][col] pad->68
    const int t = threadIdx.x;
    const int row0 = blockIdx.x * 256;
    const int col0 = blockIdx.y * 64;
    const int tc = t & 7, rg = t >> 3;
    const int c0 = tc * 8, r0 = rg * 8;

    float acc[8][8];
    #pragma unroll
    for (int i = 0; i < 8; ++i)
        #pragma unroll
        for (int j = 0; j < 8; ++j) acc[i][j] = 0.f;

    for (int kc = 0; kc < 128; kc += 32) {
        #pragma unroll
        for (int i = 0; i < 8; ++i) {
            int f4 = i * 256 + t;
            int r = f4 >> 3, kq = (f4 & 7) * 4;
            float4 v = make_float4(0.f, 0.f, 0.f, 0.f);
            if (row0 + r < N) v = *(const float4*)(x + (size_t)(row0 + r) * FH + kc + kq);
            xsT[kq][r] = v.x; xsT[kq + 1][r] = v.y;
            xsT[kq + 2][r] = v.z; xsT[kq + 3][r] = v.w;
        }
        #pragma unroll
        for (int i = 0; i < 2; ++i) {
            int f4 = i * 256 + t;
            int k = f4 >> 4, cq = (f4 & 15) * 4;
            *(float4*)&Ws[k][cq] = *(const float4*)(W + (size_t)(kc + k) * FH + col0 + cq);
        }
        __syncthreads();
        #pragma unroll 4
        for (int k = 0; k < 32; ++k) {
            float4 xa0 = *(const float4*)&xsT[k][r0];
            float4 xa1 = *(const float4*)&xsT[k][r0 + 4];
            float4 wv0 = *(const float4*)&Ws[k][c0];
            float4 wv1 = *(const float4*)&Ws[k][c0 + 4];
            float xr[8] = {xa0.x, xa0.y, xa0.z, xa0.w, xa1.x, xa1.y, xa1.z, xa1.w};
            float wc[8] = {wv0.x, wv0.y, wv0.z, wv0.w, wv1.x, wv1.y, wv1.z, wv1.w};
            #pragma unroll
            for (int i = 0; i < 8; ++i)
                #pragma unroll
                for (int j = 0; j < 8; ++j)
                    acc[i][j] = fmaf(xr[i], wc[j], acc[i][j]);
        }
        __syncthreads();
    }

    const int hg = (col0 + c0) >> 5;
    const int cl = (col0 + c0) & 31;
    float4 as0 = *(const float4*)(asrc + hg * 32 + cl);
    float4 as1 = *(const float4*)(asrc + hg * 32 + cl + 4);
    float4 ad0 = *(const float4*)(adst + hg * 32 + cl);
    float4 ad1 = *(const float4*)(adst + hg * 32 + cl + 4);
    float as[8] = {as0.x, as0.y, as0.z, as0.w, as1.x, as1.y, as1.z, as1.w};
    float ad[8] = {ad0.x, ad0.y, ad0.z, ad0.w, ad1.x, ad1.y, ad1.z, ad1.w};
    float sA[8], dA[8];
    #pragma unroll
    for (int i = 0; i < 8; ++i) {
        float s = 0.f, d = 0.f;
        #pragma unroll
        for (int j = 0; j < 8; ++j) {
            s = fmaf(acc[i][j], as[j], s);
            d = fmaf(acc[i][j], ad[j], d);
        }
        sA[i] = s; dA[i] = d;
    }
    #pragma unroll
    for (int i = 0; i < 8; ++i) {
        sA[i] += __shfl_xor(sA[i], 1, 64); sA[i] += __shfl_xor(sA[i], 2, 64);
        dA[i] += __shfl_xor(dA[i], 1, 64); dA[i] += __shfl_xor(dA[i], 2, 64);
    }
    if ((tc & 3) == 0) {
        #pragma unroll
        for (int i = 0; i < 8; ++i) {
            int row = row0 + r0 + i;
            if (row < N) { ssrc[row * 4 + hg] = sA[i]; sdst[row * 4 + hg] = dA[i]; }
        }
    }
    #pragma unroll
    for (int i = 0; i < 8; ++i) {
        int row = row0 + r0 + i;
        if (row < N) {
            __half2 ph[4];
            ph[0] = __floats2half2_rn(acc[i][0], acc[i][1]);
            ph[1] = __floats2half2_rn(acc[i][2], acc[i][3]);
            ph[2] = __floats2half2_rn(acc[i][4], acc[i][5]);
            ph[3] = __floats2half2_rn(acc[i][6], acc[i][7]);
            *(uint4*)(h1h + (size_t)row * FH + col0 + c0) = *(uint4*)ph;
        }
    }
}

// ---------------------------------------------------------------------------
// CSR build
// ---------------------------------------------------------------------------
__global__ void k_count(const int* __restrict__ ei, int E, int N, int* __restrict__ deg) {
    int i = blockIdx.x * blockDim.x + threadIdx.x;
    if (i >= E + N) return;
    int d = (i < E) ? ei[E + i] : (i - E);
    atomicAdd(&deg[d], 1);
}

__global__ __launch_bounds__(1024) void k_scan1(const int* __restrict__ deg,
                                                int* __restrict__ rowptr,
                                                int* __restrict__ blksum, int N) {
    int t = threadIdx.x;
    int i = blockIdx.x * 1024 + t;
    int v = (i < N) ? deg[i] : 0;
    int lane = t & 63, w = t >> 6;
    int incl = v;
    #pragma unroll
    for (int off = 1; off < 64; off <<= 1) {
        int tmp = __shfl_up(incl, off, 64);
        if (lane >= off) incl += tmp;
    }
    __shared__ int wsum[16];
    if (lane == 63) wsum[w] = incl;
    __syncthreads();
    if (t == 0) {
        int s = 0;
        for (int k = 0; k < 16; ++k) { int x = wsum[k]; wsum[k] = s; s += x; }
    }
    __syncthreads();
    int excl = incl - v + wsum[w];
    if (i < N) rowptr[i] = excl;
    if (t == 1023) blksum[blockIdx.x] = excl + v;
}

__global__ __launch_bounds__(1024) void k_scan2(const int* __restrict__ blksum,
                                                int* __restrict__ blkoff, int nblk) {
    int t = threadIdx.x;
    int v = (t < nblk) ? blksum[t] : 0;
    int lane = t & 63, w = t >> 6;
    int incl = v;
    #pragma unroll
    for (int off = 1; off < 64; off <<= 1) {
        int tmp = __shfl_up(incl, off, 64);
        if (lane >= off) incl += tmp;
    }
    __shared__ int wsum[16];
    if (lane == 63) wsum[w] = incl;
    __syncthreads();
    if (t == 0) {
        int s = 0;
        for (int k = 0; k < 16; ++k) { int x = wsum[k]; wsum[k] = s; s += x; }
    }
    __syncthreads();
    int excl = incl - v + wsum[w];
    if (t < nblk) blkoff[t] = excl;
    if (t == nblk - 1) blkoff[nblk] = excl + v;
}

__global__ void k_scan3(int* __restrict__ rowptr, const int* __restrict__ blkoff, int N) {
    int i = blockIdx.x * blockDim.x + threadIdx.x;
    if (i > N) return;
    if (i == N) rowptr[N] = blkoff[(N + 1023) >> 10];
    else        rowptr[i] += blkoff[i >> 10];
}

// fill: place edge into CSR slot AND precompute per-edge softmax weights
__global__ void k_fill(const int* __restrict__ ei, int E, int N,
                       const int* __restrict__ rowptr, int* __restrict__ deg,
                       const float4* __restrict__ ssrc4, const float4* __restrict__ sdst4,
                       int* __restrict__ csr, float4* __restrict__ alpha4) {
    int i = blockIdx.x * blockDim.x + threadIdx.x;
    if (i >= E + N) return;
    int s, d;
    if (i < E) { s = ei[i]; d = ei[E + i]; }
    else       { s = i - E; d = i - E; }
    int pos = atomicSub(&deg[d], 1) - 1;
    int slot = rowptr[d] + pos;
    csr[slot] = s;
    float4 sv = ssrc4[s];
    float4 dv = sdst4[d];
    float ex = sv.x + dv.x; ex = fmaxf(ex, NEG_SLOPE * ex);
    float ey = sv.y + dv.y; ey = fmaxf(ey, NEG_SLOPE * ey);
    float ez = sv.z + dv.z; ez = fmaxf(ez, NEG_SLOPE * ez);
    float ew = sv.w + dv.w; ew = fmaxf(ew, NEG_SLOPE * ew);
    float4 a;
    a.x = __expf(ex); a.y = __expf(ey); a.z = __expf(ez); a.w = __expf(ew);
    alpha4[slot] = a;
}

// ---------------------------------------------------------------------------
// Layer-1 aggregation, one wave per dst node: single dependency-free pass.
// ---------------------------------------------------------------------------
__global__ __launch_bounds__(256) void k_agg1(
    const int* __restrict__ rowptr, const int* __restrict__ csr,
    const float* __restrict__ alph, const __half* __restrict__ h1h,
    const float* __restrict__ b1, float* __restrict__ out, int N)
{
    int n = (blockIdx.x * blockDim.x + threadIdx.x) >> 6;
    int lane = threadIdx.x & 63;
    if (n >= N) return;
    int start = rowptr[n];
    int dcnt  = rowptr[n + 1] - start;
    int h = lane >> 4;

    float ax = 0.f, ay = 0.f, l = 0.f;
    const __half2* h1v = (const __half2*)h1h;
    #pragma unroll 4
    for (int j = 0; j < dcnt; ++j) {
        int idx = start + j;
        int s = csr[idx];
        float a = alph[idx * 4 + h];
        l += a;
        float2 v = __half22float2(h1v[((size_t)s << 6) + lane]);
        ax = fmaf(a, v.x, ax);
        ay = fmaf(a, v.y, ay);
    }
    float inv = 1.f / (l + 1e-16f);
    float2 b1v = ((const float2*)b1)[lane];
    float2 o;
    o.x = fmaf(ax, inv, b1v.x);
    o.y = fmaf(ay, inv, b1v.y);
    ((float2*)out)[((size_t)n << 6) + lane] = o;
}

// ---------------------------------------------------------------------------
// BN column stats stage 1: per-block partials, plain coalesced stores (no atomics)
// ---------------------------------------------------------------------------
__global__ __launch_bounds__(256) void k_bnstat(const float4* __restrict__ hb4,
                                                float* __restrict__ part_s,
                                                float* __restrict__ part_q, int N) {
    __shared__ float rs[8][128];
    __shared__ float rq[8][128];
    int t = threadIdx.x;
    int rg = t >> 5, c4 = t & 31;
    float sx = 0, sy = 0, sz = 0, sw = 0, qx = 0, qy = 0, qz = 0, qw = 0;
    for (int r = blockIdx.x * 8 + rg; r < N; r += gridDim.x * 8) {
        float4 v = hb4[(size_t)r * 32 + c4];
        sx += v.x; sy += v.y; sz += v.z; sw += v.w;
        qx = fmaf(v.x, v.x, qx); qy = fmaf(v.y, v.y, qy);
        qz = fmaf(v.z, v.z, qz); qw = fmaf(v.w, v.w, qw);
    }
    int c = c4 * 4;
    rs[rg][c] = sx; rs[rg][c+1] = sy; rs[rg][c+2] = sz; rs[rg][c+3] = sw;
    rq[rg][c] = qx; rq[rg][c+1] = qy; rq[rg][c+2] = qz; rq[rg][c+3] = qw;
    __syncthreads();
    for (int k = 4; k; k >>= 1) {
        if (rg < k) {
            rs[rg][c]   += rs[rg+k][c];   rs[rg][c+1] += rs[rg+k][c+1];
            rs[rg][c+2] += rs[rg+k][c+2]; rs[rg][c+3] += rs[rg+k][c+3];
            rq[rg][c]   += rq[rg+k][c];   rq[rg][c+1] += rq[rg+k][c+1];
            rq[rg][c+2] += rq[rg+k][c+2]; rq[rg][c+3] += rq[rg+k][c+3];
        }
        __syncthreads();
    }
    if (t < 128) {
        part_s[(size_t)blockIdx.x * 128 + t] = rs[0][t];
        part_q[(size_t)blockIdx.x * 128 + t] = rq[0][t];
    }
}

// ---------------------------------------------------------------------------
// BN stage 2: reduce NBLK_BN partials -> scale/shift. 1 block x 1024 threads,
// 8 lane-groups x 128 cols, coalesced reads, LDS tree.
// ---------------------------------------------------------------------------
__global__ __launch_bounds__(1024) void k_bnred(const float* __restrict__ part_s,
                                                const float* __restrict__ part_q,
                                                const float* __restrict__ gamma,
                                                const float* __restrict__ beta,
                                                float* __restrict__ bnscale,
                                                float* __restrict__ bnshift,
                                                float invN) {
    __shared__ float ls[8][128];
    __shared__ float lq[8][128];
    int t = threadIdx.x;
    int c = t & 127, g = t >> 7;       // 8 groups
    float s = 0.f, q = 0.f;
    for (int blk = g; blk < NBLK_BN; blk += 8) {
        s += part_s[(size_t)blk * 128 + c];
        q += part_q[(size_t)blk * 128 + c];
    }
    ls[g][c] = s; lq[g][c] = q;
    __syncthreads();
    for (int k = 4; k; k >>= 1) {
        if (g < k) { ls[g][c] += ls[g + k][c]; lq[g][c] += lq[g + k][c]; }
        __syncthreads();
    }
    if (t < 128) {
        float mu  = ls[0][t] * invN;
        float var = lq[0][t] * invN - mu * mu;
        float sc  = rsqrtf(var + BN_EPS) * gamma[t];
        bnscale[t] = sc;
        bnshift[t] = beta[t] - mu * sc;
    }
}

// ---------------------------------------------------------------------------
// Fused BN-apply + ELU + layer-2 linear + scores. Packs (h2x,h2y,ss2,sd2).
// ---------------------------------------------------------------------------
__global__ __launch_bounds__(256) void k_bn2(const float4* __restrict__ hb4,
                                             const float* __restrict__ bnscale,
                                             const float* __restrict__ bnshift,
                                             const float* __restrict__ W2,
                                             const float* __restrict__ as2,
                                             const float* __restrict__ ad2,
                                             float4* __restrict__ node2, int N) {
    int t = threadIdx.x;
    int rl = t >> 5, c4 = t & 31;
    int r = blockIdx.x * 8 + rl;
    if (r >= N) return;
    int c = c4 * 4;
    float4 sc4 = *(const float4*)(bnscale + c);
    float4 sh4 = *(const float4*)(bnshift + c);
    float4 v = hb4[(size_t)r * 32 + c4];
    float t0 = fmaf(v.x, sc4.x, sh4.x);
    float t1 = fmaf(v.y, sc4.y, sh4.y);
    float t2 = fmaf(v.z, sc4.z, sh4.z);
    float t3 = fmaf(v.w, sc4.w, sh4.w);
    t0 = t0 > 0.f ? t0 : expm1f(t0);
    t1 = t1 > 0.f ? t1 : expm1f(t1);
    t2 = t2 > 0.f ? t2 : expm1f(t2);
    t3 = t3 > 0.f ? t3 : expm1f(t3);
    float d0 = t0 * W2[c * 2]       + t1 * W2[(c + 1) * 2]
             + t2 * W2[(c + 2) * 2] + t3 * W2[(c + 3) * 2];
    float d1 = t0 * W2[c * 2 + 1]       + t1 * W2[(c + 1) * 2 + 1]
             + t2 * W2[(c + 2) * 2 + 1] + t3 * W2[(c + 3) * 2 + 1];
    #pragma unroll
    for (int off = 16; off; off >>= 1) {
        d0 += __shfl_xor(d0, off, 64);
        d1 += __shfl_xor(d1, off, 64);
    }
    if (c4 == 0) {
        float4 o;
        o.x = d0; o.y = d1;
        o.z = d0 * as2[0] + d1 * as2[1];
        o.w = d0 * ad2[0] + d1 * ad2[1];
        node2[r] = o;
    }
}

// ---------------------------------------------------------------------------
// Layer-2 aggregation: 16 lanes per node, single float4 gather per edge
// ---------------------------------------------------------------------------
__global__ __launch_bounds__(256) void k_agg2(const int* __restrict__ rowptr,
                                              const int* __restrict__ csr,
                                              const float4* __restrict__ node2,
                                              const float* __restrict__ b2,
                                              float* __restrict__ out, int N) {
    int gid = blockIdx.x * blockDim.x + threadIdx.x;
    int n = gid >> 4;
    int ln = gid & 15;
    if (n >= N) return;
    int start = rowptr[n];
    int dcnt  = rowptr[n + 1] - start;
    float sdv = node2[n].w;
    float m = -3e38f, l = 0.f, a0 = 0.f, a1 = 0.f;
    for (int j = ln; j < dcnt; j += 16) {
        int s = csr[start + j];
        float4 hv = node2[s];
        float e = hv.z + sdv;
        e = fmaxf(e, NEG_SLOPE * e);
        float nm = fmaxf(m, e);
        float sc = __expf(m - nm);
        float p  = __expf(e - nm);
        a0 = a0 * sc + p * hv.x;
        a1 = a1 * sc + p * hv.y;
        l  = l * sc + p;
        m  = nm;
    }
    #pragma unroll
    for (int off = 8; off; off >>= 1) {
        float mo  = __shfl_xor(m, off, 64);
        float lo  = __shfl_xor(l, off, 64);
        float a0o = __shfl_xor(a0, off, 64);
        float a1o = __shfl_xor(a1, off, 64);
        float nm = fmaxf(m, mo);
        float sc = __expf(m - nm), so = __expf(mo - nm);
        l  = l * sc + lo * so;
        a0 = a0 * sc + a0o * so;
        a1 = a1 * sc + a1o * so;
        m  = nm;
    }
    if (ln == 0) {
        float inv = 1.f / (l + 1e-16f);
        float2 o;
        o.x = fmaf(a0, inv, b2[0]);
        o.y = fmaf(a1, inv, b2[1]);
        ((float2*)out)[n] = o;
    }
}

// ---------------------------------------------------------------------------
extern "C" void kernel_launch(void* const* d_in, const int* in_sizes, int n_in,
                              void* d_out, int out_size, void* d_ws, size_t ws_size,
                              hipStream_t stream) {
    const int N = in_sizes[0] / FH;       // 50000
    const int E = in_sizes[1] / 2;        // 800000
    const int Etot = E + N;
    const int nblk = (N + 1023) >> 10;

    const float* x     = (const float*)d_in[0];
    const int*   ei    = (const int*)d_in[1];
    const float* W1    = (const float*)d_in[2];
    const float* asrc1 = (const float*)d_in[3];
    const float* adst1 = (const float*)d_in[4];
    const float* b1    = (const float*)d_in[5];
    const float* gamma = (const float*)d_in[6];
    const float* beta  = (const float*)d_in[7];
    const float* W2    = (const float*)d_in[8];
    const float* as2   = (const float*)d_in[9];
    const float* ad2   = (const float*)d_in[10];
    const float* b2    = (const float*)d_in[11];
    float* out = (float*)d_out;

    char* ws = (char*)d_ws;
    size_t off = 0;
    auto nxt = [&](size_t bytes) {
        size_t o = off;
        off += (bytes + 255) & ~(size_t)255;
        return o;
    };
    __half* h1h    = (__half*)(ws + nxt((size_t)N * FH * 2));
    float* hb      = (float*)(ws + nxt((size_t)N * FH * 4));
    float* ssrc1   = (float*)(ws + nxt((size_t)N * 4 * 4));
    float* sdst1   = (float*)(ws + nxt((size_t)N * 4 * 4));
    float* node2   = (float*)(ws + nxt((size_t)N * 4 * 4));
    float* alpha   = (float*)(ws + nxt((size_t)Etot * 4 * 4));
    float* part_s  = (float*)(ws + nxt((size_t)NBLK_BN * 128 * 4));
    float* part_q  = (float*)(ws + nxt((size_t)NBLK_BN * 128 * 4));
    float* bnscale = (float*)(ws + nxt(128 * 4));
    float* bnshift = (float*)(ws + nxt(128 * 4));
    size_t zoff0   = off;
    int*   deg     = (int*)(ws + nxt((size_t)N * 4));
    size_t zbytes  = off - zoff0;
    int*   rowptr  = (int*)(ws + nxt((size_t)(N + 1) * 4));
    int*   csr     = (int*)(ws + nxt((size_t)Etot * 4));
    int*   blksum  = (int*)(ws + nxt((size_t)nblk * 4));
    int*   blkoff  = (int*)(ws + nxt((size_t)(nblk + 1) * 4));

    hipMemsetAsync(ws + zoff0, 0, zbytes, stream);

    dim3 g1((N + 255) / 256, 2);
    k_gemm1<<<g1, 256, 0, stream>>>(x, W1, asrc1, adst1, h1h, ssrc1, sdst1, N);
    k_count<<<(Etot + 255) / 256, 256, 0, stream>>>(ei, E, N, deg);
    k_scan1<<<nblk, 1024, 0, stream>>>(deg, rowptr, blksum, N);
    k_scan2<<<1, 1024, 0, stream>>>(blksum, blkoff, nblk);
    k_scan3<<<(N + 256) / 256, 256, 0, stream>>>(rowptr, blkoff, N);
    k_fill<<<(Etot + 255) / 256, 256, 0, stream>>>(ei, E, N, rowptr, deg,
                                                   (const float4*)ssrc1,
                                                   (const float4*)sdst1,
                                                   csr, (float4*)alpha);
    k_agg1<<<(N + 3) / 4, 256, 0, stream>>>(rowptr, csr, alpha, h1h, b1, hb, N);
    k_bnstat<<<NBLK_BN, 256, 0, stream>>>((const float4*)hb, part_s, part_q, N);
    k_bnred<<<1, 1024, 0, stream>>>(part_s, part_q, gamma, beta, bnscale, bnshift,
                                    1.0f / (float)N);
    k_bn2<<<(N + 7) / 8, 256, 0, stream>>>((const float4*)hb, bnscale, bnshift,
                                           W2, as2, ad2, (float4*)node2, N);
    k_agg2<<<(N * 16 + 255) / 256, 256, 0, stream>>>(rowptr, csr, (const float4*)node2,
                                                     b2, out, N);
}

// Round 11
// 291.819 us; speedup vs baseline: 1.7813x; 1.0047x over previous
//
#include <hip/hip_runtime.h>
#include <hip/hip_bf16.h>
#include <hip/hip_fp16.h>
#include <math.h>

#define FH 128     // hidden = heads(4) * C(32)
#define NEG_SLOPE 0.2f
#define BN_EPS 1e-5f
#define NBLK_BN 512

// ---------------------------------------------------------------------------
// GEMM1: h1 = x @ W1 [N,128]x[128,128], fused per-(node,head) attention scores.
// h1 stored ONLY as packed fp16. Tile 256 rows x 64 cols, BK=32, 256 threads,
// 8x8 microtile, x staged TRANSPOSED so both operands are b128 LDS reads.
// ---------------------------------------------------------------------------
__global__ __launch_bounds__(256) void k_gemm1(
    const float* __restrict__ x, const float* __restrict__ W,
    const float* __restrict__ asrc, const float* __restrict__ adst,
    __half* __restrict__ h1h, float* __restrict__ ssrc, float* __restrict__ sdst,
    int N)
{
    __shared__ float xsT[32][260];   // [k][row] pad->260
    __shared__ float Ws[32][68];     // [k][col] pad->68
    const int t = threadIdx.x;
    const int row0 = blockIdx.x * 256;
    const int col0 = blockIdx.y * 64;
    const int tc = t & 7, rg = t >> 3;
    const int c0 = tc * 8, r0 = rg * 8;

    float acc[8][8];
    #pragma unroll
    for (int i = 0; i < 8; ++i)
        #pragma unroll
        for (int j = 0; j < 8; ++j) acc[i][j] = 0.f;

    for (int kc = 0; kc < 128; kc += 32) {
        #pragma unroll
        for (int i = 0; i < 8; ++i) {
            int f4 = i * 256 + t;
            int r = f4 >> 3, kq = (f4 & 7) * 4;
            float4 v = make_float4(0.f, 0.f, 0.f, 0.f);
            if (row0 + r < N) v = *(const float4*)(x + (size_t)(row0 + r) * FH + kc + kq);
            xsT[kq][r] = v.x; xsT[kq + 1][r] = v.y;
            xsT[kq + 2][r] = v.z; xsT[kq + 3][r] = v.w;
        }
        #pragma unroll
        for (int i = 0; i < 2; ++i) {
            int f4 = i * 256 + t;
            int k = f4 >> 4, cq = (f4 & 15) * 4;
            *(float4*)&Ws[k][cq] = *(const float4*)(W + (size_t)(kc + k) * FH + col0 + cq);
        }
        __syncthreads();
        #pragma unroll 4
        for (int k = 0; k < 32; ++k) {
            float4 xa0 = *(const float4*)&xsT[k][r0];
            float4 xa1 = *(const float4*)&xsT[k][r0 + 4];
            float4 wv0 = *(const float4*)&Ws[k][c0];
            float4 wv1 = *(const float4*)&Ws[k][c0 + 4];
            float xr[8] = {xa0.x, xa0.y, xa0.z, xa0.w, xa1.x, xa1.y, xa1.z, xa1.w};
            float wc[8] = {wv0.x, wv0.y, wv0.z, wv0.w, wv1.x, wv1.y, wv1.z, wv1.w};
            #pragma unroll
            for (int i = 0; i < 8; ++i)
                #pragma unroll
                for (int j = 0; j < 8; ++j)
                    acc[i][j] = fmaf(xr[i], wc[j], acc[i][j]);
        }
        __syncthreads();
    }

    const int hg = (col0 + c0) >> 5;
    const int cl = (col0 + c0) & 31;
    float4 as0 = *(const float4*)(asrc + hg * 32 + cl);
    float4 as1 = *(const float4*)(asrc + hg * 32 + cl + 4);
    float4 ad0 = *(const float4*)(adst + hg * 32 + cl);
    float4 ad1 = *(const float4*)(adst + hg * 32 + cl + 4);
    float as[8] = {as0.x, as0.y, as0.z, as0.w, as1.x, as1.y, as1.z, as1.w};
    float ad[8] = {ad0.x, ad0.y, ad0.z, ad0.w, ad1.x, ad1.y, ad1.z, ad1.w};
    float sA[8], dA[8];
    #pragma unroll
    for (int i = 0; i < 8; ++i) {
        float s = 0.f, d = 0.f;
        #pragma unroll
        for (int j = 0; j < 8; ++j) {
            s = fmaf(acc[i][j], as[j], s);
            d = fmaf(acc[i][j], ad[j], d);
        }
        sA[i] = s; dA[i] = d;
    }
    #pragma unroll
    for (int i = 0; i < 8; ++i) {
        sA[i] += __shfl_xor(sA[i], 1, 64); sA[i] += __shfl_xor(sA[i], 2, 64);
        dA[i] += __shfl_xor(dA[i], 1, 64); dA[i] += __shfl_xor(dA[i], 2, 64);
    }
    if ((tc & 3) == 0) {
        #pragma unroll
        for (int i = 0; i < 8; ++i) {
            int row = row0 + r0 + i;
            if (row < N) { ssrc[row * 4 + hg] = sA[i]; sdst[row * 4 + hg] = dA[i]; }
        }
    }
    #pragma unroll
    for (int i = 0; i < 8; ++i) {
        int row = row0 + r0 + i;
        if (row < N) {
            __half2 ph[4];
            ph[0] = __floats2half2_rn(acc[i][0], acc[i][1]);
            ph[1] = __floats2half2_rn(acc[i][2], acc[i][3]);
            ph[2] = __floats2half2_rn(acc[i][4], acc[i][5]);
            ph[3] = __floats2half2_rn(acc[i][6], acc[i][7]);
            *(uint4*)(h1h + (size_t)row * FH + col0 + c0) = *(uint4*)ph;
        }
    }
}

// ---------------------------------------------------------------------------
// CSR build
// ---------------------------------------------------------------------------
__global__ void k_count(const int* __restrict__ ei, int E, int N, int* __restrict__ deg) {
    int i = blockIdx.x * blockDim.x + threadIdx.x;
    if (i >= E + N) return;
    int d = (i < E) ? ei[E + i] : (i - E);
    atomicAdd(&deg[d], 1);
}

__global__ __launch_bounds__(1024) void k_scan1(const int* __restrict__ deg,
                                                int* __restrict__ rowptr,
                                                int* __restrict__ blksum, int N) {
    int t = threadIdx.x;
    int i = blockIdx.x * 1024 + t;
    int v = (i < N) ? deg[i] : 0;
    int lane = t & 63, w = t >> 6;
    int incl = v;
    #pragma unroll
    for (int off = 1; off < 64; off <<= 1) {
        int tmp = __shfl_up(incl, off, 64);
        if (lane >= off) incl += tmp;
    }
    __shared__ int wsum[16];
    if (lane == 63) wsum[w] = incl;
    __syncthreads();
    if (t == 0) {
        int s = 0;
        for (int k = 0; k < 16; ++k) { int x = wsum[k]; wsum[k] = s; s += x; }
    }
    __syncthreads();
    int excl = incl - v + wsum[w];
    if (i < N) rowptr[i] = excl;
    if (t == 1023) blksum[blockIdx.x] = excl + v;
}

__global__ __launch_bounds__(1024) void k_scan2(const int* __restrict__ blksum,
                                                int* __restrict__ blkoff, int nblk) {
    int t = threadIdx.x;
    int v = (t < nblk) ? blksum[t] : 0;
    int lane = t & 63, w = t >> 6;
    int incl = v;
    #pragma unroll
    for (int off = 1; off < 64; off <<= 1) {
        int tmp = __shfl_up(incl, off, 64);
        if (lane >= off) incl += tmp;
    }
    __shared__ int wsum[16];
    if (lane == 63) wsum[w] = incl;
    __syncthreads();
    if (t == 0) {
        int s = 0;
        for (int k = 0; k < 16; ++k) { int x = wsum[k]; wsum[k] = s; s += x; }
    }
    __syncthreads();
    int excl = incl - v + wsum[w];
    if (t < nblk) blkoff[t] = excl;
    if (t == nblk - 1) blkoff[nblk] = excl + v;
}

__global__ void k_scan3(int* __restrict__ rowptr, const int* __restrict__ blkoff, int N) {
    int i = blockIdx.x * blockDim.x + threadIdx.x;
    if (i > N) return;
    if (i == N) rowptr[N] = blkoff[(N + 1023) >> 10];
    else        rowptr[i] += blkoff[i >> 10];
}

// fill: single scattered 4B store per edge (alpha no longer materialized)
__global__ void k_fill(const int* __restrict__ ei, int E, int N,
                       const int* __restrict__ rowptr, int* __restrict__ deg,
                       int* __restrict__ csr) {
    int i = blockIdx.x * blockDim.x + threadIdx.x;
    if (i >= E + N) return;
    int s, d;
    if (i < E) { s = ei[i]; d = ei[E + i]; }
    else       { s = i - E; d = i - E; }
    int pos = atomicSub(&deg[d], 1) - 1;
    csr[rowptr[d] + pos] = s;
}

// ---------------------------------------------------------------------------
// Layer-1 aggregation, one wave per dst node, 64-edge chunks:
// phase 1 (lane-parallel): lane j gathers ssrc4[csr[start+j]], computes
//   alpha4 = exp(leaky(ssrc+sdst)) (4 exp/edge TOTAL), stashes (alpha4, src)
//   in wave-private LDS — no barrier needed (same-wave lgkmcnt ordering).
// phase 2 (sequential, dependency-free): alpha from LDS broadcast + fp16 h1
//   gather + 2 FMA; l += alpha; divide once at the end.
// ---------------------------------------------------------------------------
__global__ __launch_bounds__(256) void k_agg1(
    const int* __restrict__ rowptr, const int* __restrict__ csr,
    const float4* __restrict__ ssrc4, const float4* __restrict__ sdst4,
    const __half* __restrict__ h1h, const float* __restrict__ b1,
    float* __restrict__ out, int N)
{
    __shared__ __align__(16) float lal[4][256];   // per wave: 64 slots x 4 heads
    __shared__ int lsrc[4][64];
    int wid  = threadIdx.x >> 6;
    int lane = threadIdx.x & 63;
    int n = (blockIdx.x * blockDim.x + threadIdx.x) >> 6;
    if (n >= N) return;
    int start = rowptr[n];
    int dcnt  = rowptr[n + 1] - start;
    int h = lane >> 4;

    float4 dv = sdst4[n];
    float ax = 0.f, ay = 0.f, l = 0.f;
    const __half2* h1v = (const __half2*)h1h;

    for (int j0 = 0; j0 < dcnt; j0 += 64) {
        int j = j0 + lane;
        if (j < dcnt) {
            int s = csr[start + j];
            float4 sv = ssrc4[s];
            float ex = sv.x + dv.x; ex = fmaxf(ex, NEG_SLOPE * ex);
            float ey = sv.y + dv.y; ey = fmaxf(ey, NEG_SLOPE * ey);
            float ez = sv.z + dv.z; ez = fmaxf(ez, NEG_SLOPE * ez);
            float ew = sv.w + dv.w; ew = fmaxf(ew, NEG_SLOPE * ew);
            float4 a4;
            a4.x = __expf(ex); a4.y = __expf(ey);
            a4.z = __expf(ez); a4.w = __expf(ew);
            *(float4*)&lal[wid][lane * 4] = a4;
            lsrc[wid][lane] = s;
        }
        int jend = dcnt - j0; if (jend > 64) jend = 64;
        #pragma unroll 4
        for (int jj = 0; jj < jend; ++jj) {
            float a = lal[wid][jj * 4 + h];
            int s = lsrc[wid][jj];
            l += a;
            float2 v = __half22float2(h1v[((size_t)s << 6) + lane]);
            ax = fmaf(a, v.x, ax);
            ay = fmaf(a, v.y, ay);
        }
    }
    float inv = 1.f / (l + 1e-16f);
    float2 b1v = ((const float2*)b1)[lane];
    float2 o;
    o.x = fmaf(ax, inv, b1v.x);
    o.y = fmaf(ay, inv, b1v.y);
    ((float2*)out)[((size_t)n << 6) + lane] = o;
}

// ---------------------------------------------------------------------------
// BN column stats stage 1: per-block partials, plain coalesced stores
// ---------------------------------------------------------------------------
__global__ __launch_bounds__(256) void k_bnstat(const float4* __restrict__ hb4,
                                                float* __restrict__ part_s,
                                                float* __restrict__ part_q, int N) {
    __shared__ float rs[8][128];
    __shared__ float rq[8][128];
    int t = threadIdx.x;
    int rg = t >> 5, c4 = t & 31;
    float sx = 0, sy = 0, sz = 0, sw = 0, qx = 0, qy = 0, qz = 0, qw = 0;
    for (int r = blockIdx.x * 8 + rg; r < N; r += gridDim.x * 8) {
        float4 v = hb4[(size_t)r * 32 + c4];
        sx += v.x; sy += v.y; sz += v.z; sw += v.w;
        qx = fmaf(v.x, v.x, qx); qy = fmaf(v.y, v.y, qy);
        qz = fmaf(v.z, v.z, qz); qw = fmaf(v.w, v.w, qw);
    }
    int c = c4 * 4;
    rs[rg][c] = sx; rs[rg][c+1] = sy; rs[rg][c+2] = sz; rs[rg][c+3] = sw;
    rq[rg][c] = qx; rq[rg][c+1] = qy; rq[rg][c+2] = qz; rq[rg][c+3] = qw;
    __syncthreads();
    for (int k = 4; k; k >>= 1) {
        if (rg < k) {
            rs[rg][c]   += rs[rg+k][c];   rs[rg][c+1] += rs[rg+k][c+1];
            rs[rg][c+2] += rs[rg+k][c+2]; rs[rg][c+3] += rs[rg+k][c+3];
            rq[rg][c]   += rq[rg+k][c];   rq[rg][c+1] += rq[rg+k][c+1];
            rq[rg][c+2] += rq[rg+k][c+2]; rq[rg][c+3] += rq[rg+k][c+3];
        }
        __syncthreads();
    }
    if (t < 128) {
        part_s[(size_t)blockIdx.x * 128 + t] = rs[0][t];
        part_q[(size_t)blockIdx.x * 128 + t] = rq[0][t];
    }
}

// ---------------------------------------------------------------------------
// BN stage 2: reduce partials -> scale/shift
// ---------------------------------------------------------------------------
__global__ __launch_bounds__(1024) void k_bnred(const float* __restrict__ part_s,
                                                const float* __restrict__ part_q,
                                                const float* __restrict__ gamma,
                                                const float* __restrict__ beta,
                                                float* __restrict__ bnscale,
                                                float* __restrict__ bnshift,
                                                float invN) {
    __shared__ float ls[8][128];
    __shared__ float lq[8][128];
    int t = threadIdx.x;
    int c = t & 127, g = t >> 7;
    float s = 0.f, q = 0.f;
    for (int blk = g; blk < NBLK_BN; blk += 8) {
        s += part_s[(size_t)blk * 128 + c];
        q += part_q[(size_t)blk * 128 + c];
    }
    ls[g][c] = s; lq[g][c] = q;
    __syncthreads();
    for (int k = 4; k; k >>= 1) {
        if (g < k) { ls[g][c] += ls[g + k][c]; lq[g][c] += lq[g + k][c]; }
        __syncthreads();
    }
    if (t < 128) {
        float mu  = ls[0][t] * invN;
        float var = lq[0][t] * invN - mu * mu;
        float sc  = rsqrtf(var + BN_EPS) * gamma[t];
        bnscale[t] = sc;
        bnshift[t] = beta[t] - mu * sc;
    }
}

// ---------------------------------------------------------------------------
// Fused BN-apply + ELU + layer-2 linear + scores. Packs (h2x,h2y,ss2,sd2).
// ---------------------------------------------------------------------------
__global__ __launch_bounds__(256) void k_bn2(const float4* __restrict__ hb4,
                                             const float* __restrict__ bnscale,
                                             const float* __restrict__ bnshift,
                                             const float* __restrict__ W2,
                                             const float* __restrict__ as2,
                                             const float* __restrict__ ad2,
                                             float4* __restrict__ node2, int N) {
    int t = threadIdx.x;
    int rl = t >> 5, c4 = t & 31;
    int r = blockIdx.x * 8 + rl;
    if (r >= N) return;
    int c = c4 * 4;
    float4 sc4 = *(const float4*)(bnscale + c);
    float4 sh4 = *(const float4*)(bnshift + c);
    float4 v = hb4[(size_t)r * 32 + c4];
    float t0 = fmaf(v.x, sc4.x, sh4.x);
    float t1 = fmaf(v.y, sc4.y, sh4.y);
    float t2 = fmaf(v.z, sc4.z, sh4.z);
    float t3 = fmaf(v.w, sc4.w, sh4.w);
    t0 = t0 > 0.f ? t0 : expm1f(t0);
    t1 = t1 > 0.f ? t1 : expm1f(t1);
    t2 = t2 > 0.f ? t2 : expm1f(t2);
    t3 = t3 > 0.f ? t3 : expm1f(t3);
    float d0 = t0 * W2[c * 2]       + t1 * W2[(c + 1) * 2]
             + t2 * W2[(c + 2) * 2] + t3 * W2[(c + 3) * 2];
    float d1 = t0 * W2[c * 2 + 1]       + t1 * W2[(c + 1) * 2 + 1]
             + t2 * W2[(c + 2) * 2 + 1] + t3 * W2[(c + 3) * 2 + 1];
    #pragma unroll
    for (int off = 16; off; off >>= 1) {
        d0 += __shfl_xor(d0, off, 64);
        d1 += __shfl_xor(d1, off, 64);
    }
    if (c4 == 0) {
        float4 o;
        o.x = d0; o.y = d1;
        o.z = d0 * as2[0] + d1 * as2[1];
        o.w = d0 * ad2[0] + d1 * ad2[1];
        node2[r] = o;
    }
}

// ---------------------------------------------------------------------------
// Layer-2 aggregation: 16 lanes per node, single float4 gather per edge
// ---------------------------------------------------------------------------
__global__ __launch_bounds__(256) void k_agg2(const int* __restrict__ rowptr,
                                              const int* __restrict__ csr,
                                              const float4* __restrict__ node2,
                                              const float* __restrict__ b2,
                                              float* __restrict__ out, int N) {
    int gid = blockIdx.x * blockDim.x + threadIdx.x;
    int n = gid >> 4;
    int ln = gid & 15;
    if (n >= N) return;
    int start = rowptr[n];
    int dcnt  = rowptr[n + 1] - start;
    float sdv = node2[n].w;
    float m = -3e38f, l = 0.f, a0 = 0.f, a1 = 0.f;
    for (int j = ln; j < dcnt; j += 16) {
        int s = csr[start + j];
        float4 hv = node2[s];
        float e = hv.z + sdv;
        e = fmaxf(e, NEG_SLOPE * e);
        float nm = fmaxf(m, e);
        float sc = __expf(m - nm);
        float p  = __expf(e - nm);
        a0 = a0 * sc + p * hv.x;
        a1 = a1 * sc + p * hv.y;
        l  = l * sc + p;
        m  = nm;
    }
    #pragma unroll
    for (int off = 8; off; off >>= 1) {
        float mo  = __shfl_xor(m, off, 64);
        float lo  = __shfl_xor(l, off, 64);
        float a0o = __shfl_xor(a0, off, 64);
        float a1o = __shfl_xor(a1, off, 64);
        float nm = fmaxf(m, mo);
        float sc = __expf(m - nm), so = __expf(mo - nm);
        l  = l * sc + lo * so;
        a0 = a0 * sc + a0o * so;
        a1 = a1 * sc + a1o * so;
        m  = nm;
    }
    if (ln == 0) {
        float inv = 1.f / (l + 1e-16f);
        float2 o;
        o.x = fmaf(a0, inv, b2[0]);
        o.y = fmaf(a1, inv, b2[1]);
        ((float2*)out)[n] = o;
    }
}

// ---------------------------------------------------------------------------
extern "C" void kernel_launch(void* const* d_in, const int* in_sizes, int n_in,
                              void* d_out, int out_size, void* d_ws, size_t ws_size,
                              hipStream_t stream) {
    const int N = in_sizes[0] / FH;       // 50000
    const int E = in_sizes[1] / 2;        // 800000
    const int Etot = E + N;
    const int nblk = (N + 1023) >> 10;

    const float* x     = (const float*)d_in[0];
    const int*   ei    = (const int*)d_in[1];
    const float* W1    = (const float*)d_in[2];
    const float* asrc1 = (const float*)d_in[3];
    const float* adst1 = (const float*)d_in[4];
    const float* b1    = (const float*)d_in[5];
    const float* gamma = (const float*)d_in[6];
    const float* beta  = (const float*)d_in[7];
    const float* W2    = (const float*)d_in[8];
    const float* as2   = (const float*)d_in[9];
    const float* ad2   = (const float*)d_in[10];
    const float* b2    = (const float*)d_in[11];
    float* out = (float*)d_out;

    char* ws = (char*)d_ws;
    size_t off = 0;
    auto nxt = [&](size_t bytes) {
        size_t o = off;
        off += (bytes + 255) & ~(size_t)255;
        return o;
    };
    __half* h1h    = (__half*)(ws + nxt((size_t)N * FH * 2));
    float* hb      = (float*)(ws + nxt((size_t)N * FH * 4));
    float* ssrc1   = (float*)(ws + nxt((size_t)N * 4 * 4));
    float* sdst1   = (float*)(ws + nxt((size_t)N * 4 * 4));
    float* node2   = (float*)(ws + nxt((size_t)N * 4 * 4));
    float* part_s  = (float*)(ws + nxt((size_t)NBLK_BN * 128 * 4));
    float* part_q  = (float*)(ws + nxt((size_t)NBLK_BN * 128 * 4));
    float* bnscale = (float*)(ws + nxt(128 * 4));
    float* bnshift = (float*)(ws + nxt(128 * 4));
    size_t zoff0   = off;
    int*   deg     = (int*)(ws + nxt((size_t)N * 4));
    size_t zbytes  = off - zoff0;
    int*   rowptr  = (int*)(ws + nxt((size_t)(N + 1) * 4));
    int*   csr     = (int*)(ws + nxt((size_t)Etot * 4));
    int*   blksum  = (int*)(ws + nxt((size_t)nblk * 4));
    int*   blkoff  = (int*)(ws + nxt((size_t)(nblk + 1) * 4));

    hipMemsetAsync(ws + zoff0, 0, zbytes, stream);

    dim3 g1((N + 255) / 256, 2);
    k_gemm1<<<g1, 256, 0, stream>>>(x, W1, asrc1, adst1, h1h, ssrc1, sdst1, N);
    k_count<<<(Etot + 255) / 256, 256, 0, stream>>>(ei, E, N, deg);
    k_scan1<<<nblk, 1024, 0, stream>>>(deg, rowptr, blksum, N);
    k_scan2<<<1, 1024, 0, stream>>>(blksum, blkoff, nblk);
    k_scan3<<<(N + 256) / 256, 256, 0, stream>>>(rowptr, blkoff, N);
    k_fill<<<(Etot + 255) / 256, 256, 0, stream>>>(ei, E, N, rowptr, deg, csr);
    k_agg1<<<(N + 3) / 4, 256, 0, stream>>>(rowptr, csr, (const float4*)ssrc1,
                                            (const float4*)sdst1, h1h, b1, hb, N);
    k_bnstat<<<NBLK_BN, 256, 0, stream>>>((const float4*)hb, part_s, part_q, N);
    k_bnred<<<1, 1024, 0, stream>>>(part_s, part_q, gamma, beta, bnscale, bnshift,
                                    1.0f / (float)N);
    k_bn2<<<(N + 7) / 8, 256, 0, stream>>>((const float4*)hb, bnscale, bnshift,
                                           W2, as2, ad2, (float4*)node2, N);
    k_agg2<<<(N * 16 + 255) / 256, 256, 0, stream>>>(rowptr, csr, (const float4*)node2,
                                                     b2, out, N);
}